// Round 4
// baseline (1002.006 us; speedup 1.0000x reference)
//
#include <hip/hip_runtime.h>
#include <hip/hip_bf16.h>
#include <math.h>

#define NGRAPH 64
#define EPSV 1e-6f

__device__ __forceinline__ unsigned enc_f32(float f){
    unsigned u = __float_as_uint(f);
    return (u & 0x80000000u) ? ~u : (u | 0x80000000u);
}
__device__ __forceinline__ float dec_f32(unsigned u){
    return (u & 0x80000000u) ? __uint_as_float(u & 0x7FFFFFFFu) : __uint_as_float(~u);
}

// ---------------- CSR build ----------------
// node histogram + bucket histogram in one pass over tgt
__global__ __launch_bounds__(256) void k_hist_b(const int* __restrict__ tgt,
                                                int* __restrict__ cnt,
                                                int* __restrict__ bcnt,
                                                int E, int shift){
    __shared__ int h[1024];
    int t = threadIdx.x;
    for(int i=t;i<1024;i+=256) h[i]=0;
    __syncthreads();
    int i = blockIdx.x*256 + t;
    int stride = gridDim.x*256;
    for(; i<E; i+=stride){
        int tt = tgt[i];
        atomicAdd(&cnt[tt], 1);
        atomicAdd(&h[tt>>shift], 1);
    }
    __syncthreads();
    for(int j=t;j<1024;j+=256){
        int v = h[j];
        if(v) atomicAdd(&bcnt[j], v);
    }
}

__global__ __launch_bounds__(256) void k_scan1(const int* __restrict__ cnt, int* __restrict__ bsum, int N){
    __shared__ int red[256];
    int t = threadIdx.x;
    int i = blockIdx.x*256 + t;
    int v = (i<N) ? cnt[i] : 0;
    red[t] = v; __syncthreads();
    for(int off=128; off>0; off>>=1){
        if(t<off) red[t] += red[t+off];
        __syncthreads();
    }
    if(t==0) bsum[blockIdx.x] = red[0];
}

__global__ __launch_bounds__(512) void k_scan2(int* __restrict__ bsum, int nb){
    __shared__ int s[512];
    int t = threadIdx.x;
    int v = (t<nb) ? bsum[t] : 0;
    s[t] = v; __syncthreads();
    for(int off=1; off<512; off<<=1){
        int a = (t>=off) ? s[t-off] : 0;
        __syncthreads();
        s[t] += a;
        __syncthreads();
    }
    if(t<nb) bsum[t] = s[t] - v;
}

__global__ __launch_bounds__(256) void k_scan3(const int* __restrict__ cnt, const int* __restrict__ bsum,
                                               int* __restrict__ row_start, int* __restrict__ cursor, int N){
    __shared__ int s[256];
    int t = threadIdx.x;
    int i = blockIdx.x*256 + t;
    int v = (i<N) ? cnt[i] : 0;
    s[t] = v; __syncthreads();
    for(int off=1; off<256; off<<=1){
        int a = (t>=off) ? s[t-off] : 0;
        __syncthreads();
        s[t] += a;
        __syncthreads();
    }
    int ex = s[t] - v + bsum[blockIdx.x];
    if(i<N){ row_start[i] = ex; cursor[i] = ex; }
    if(i==N-1) row_start[N] = ex + v;
}

// scan 1024 bucket counts; boff = exclusive prefix, bcur = copy for ticketing
__global__ __launch_bounds__(1024) void k_bscan(const int* __restrict__ bcnt,
                                                int* __restrict__ bcur){
    __shared__ int s[1024];
    int t = threadIdx.x;
    int v = bcnt[t];
    s[t] = v; __syncthreads();
    for(int off=1; off<1024; off<<=1){
        int a = (t>=off) ? s[t-off] : 0;
        __syncthreads();
        s[t] += a;
        __syncthreads();
    }
    bcur[t] = s[t] - v;
}

// scatter edges into bucket-ordered ebuf (semi-sequential writes per bucket)
__global__ __launch_bounds__(256) void k_bscat(const int* __restrict__ src, const int* __restrict__ tgt,
                                               int* __restrict__ bcur, int2* __restrict__ ebuf,
                                               int E, int shift){
    int i = blockIdx.x*256 + threadIdx.x;
    int stride = gridDim.x*256;
    for(; i<E; i+=stride){
        int ss = src[i], tt = tgt[i];
        int p = atomicAdd(&bcur[tt>>shift], 1);
        ebuf[p] = make_int2(ss, tt);
    }
}

// within-bucket node scatter: reads are sequential, writes cluster in ~8KB windows
__global__ __launch_bounds__(256) void k_nscat(const int2* __restrict__ ebuf,
                                               int* __restrict__ cursor, int* __restrict__ sorted_src,
                                               int E){
    int i = blockIdx.x*256 + threadIdx.x;
    int stride = gridDim.x*256;
    for(; i<E; i+=stride){
        int2 e = ebuf[i];
        int pos = atomicAdd(&cursor[e.y], 1);
        sorted_src[pos] = e.x;
    }
}

// ---------------- per-layer node transform (+ node-max of s1,s2) ----------------
template<int DI, int DO>
__global__ __launch_bounds__(256) void k_node_transform_t(
    const float* __restrict__ x, const float* __restrict__ fw,
    const float* __restrict__ ww,
    float* __restrict__ u, float* __restrict__ v,
    float* __restrict__ s1, float* __restrict__ s2,
    unsigned* __restrict__ amax2, int N)
{
    int n0 = blockIdx.x*256 + threadIdx.x;
    bool act = n0 < N;
    int n = act ? n0 : N-1;
    float xr[DI];
    #pragma unroll
    for(int k4=0;k4<DI/4;k4++){
        float4 t = *reinterpret_cast<const float4*>(&x[(size_t)n*DI + k4*4]);
        xr[k4*4+0]=t.x; xr[k4*4+1]=t.y; xr[k4*4+2]=t.z; xr[k4*4+3]=t.w;
    }
    float p1=0.f, p2=0.f;
    #pragma unroll
    for(int k=0;k<DI;k++){
        p1 = fmaf(xr[k], ww[k],    p1);
        p2 = fmaf(xr[k], ww[DI+k], p2);
    }
    float acc[DO];
    #pragma unroll
    for(int c=0;c<DO;c++) acc[c]=0.f;
    #pragma unroll
    for(int k=0;k<DI;k++){
        float xk = xr[k];
        #pragma unroll
        for(int c=0;c<DO;c++) acc[c] = fmaf(xk, fw[k*DO+c], acc[c]);
    }
    if(act){
        s1[n] = p1; s2[n] = p2;
        #pragma unroll
        for(int c4=0;c4<DO/4;c4++)
            *reinterpret_cast<float4*>(&u[(size_t)n*DO + c4*4]) =
                make_float4(acc[c4*4],acc[c4*4+1],acc[c4*4+2],acc[c4*4+3]);
    }
    #pragma unroll
    for(int c=0;c<DO;c++) acc[c]=0.f;
    #pragma unroll
    for(int k=0;k<DI;k++){
        float xk = xr[k];
        #pragma unroll
        for(int c=0;c<DO;c++) acc[c] = fmaf(xk, fw[(DI+k)*DO+c], acc[c]);
    }
    if(act){
        #pragma unroll
        for(int c4=0;c4<DO/4;c4++)
            *reinterpret_cast<float4*>(&v[(size_t)n*DO + c4*4]) =
                make_float4(acc[c4*4],acc[c4*4+1],acc[c4*4+2],acc[c4*4+3]);
    }
    // wave-reduce node maxima of s1,s2 (softmax shift = max_s1 + max_s2 upper bound;
    // shift-invariant up to the +eps term, error ~1e-5 relative)
    float m1 = act ? p1 : -3.4e38f;
    float m2 = act ? p2 : -3.4e38f;
    for(int off=32; off>0; off>>=1){
        m1 = fmaxf(m1, __shfl_xor(m1, off));
        m2 = fmaxf(m2, __shfl_xor(m2, off));
    }
    if((threadIdx.x & 63)==0){
        atomicMax(&amax2[0], enc_f32(m1));
        atomicMax(&amax2[1], enc_f32(m2));
    }
}

// ---------------- edge softmax + aggregate (CSR, wave per node) ----------------
template<int DO>
__global__ __launch_bounds__(256) void k_aggregate_t(
    const int* __restrict__ row_start, const int* __restrict__ sorted_src,
    const float* __restrict__ u, const float* __restrict__ v,
    const float* __restrict__ s1, const float* __restrict__ s2,
    const float* __restrict__ fb,
    const unsigned* __restrict__ amax2,
    float* __restrict__ xout, int N)
{
    constexpr int PN = 64 / DO;           // edge groups per wave (1 or 2)
    float amax = dec_f32(amax2[0]) + dec_f32(amax2[1]);
    int lane = threadIdx.x & 63;
    int wid  = threadIdx.x >> 6;
    int c    = lane & (DO-1);
    int grp  = lane >> (DO==32 ? 5 : 6);
    float fbc = fb[c];
    int gw = blockIdx.x*4 + wid;
    int nwaves = gridDim.x*4;
    for(int n=gw; n<N; n+=nwaves){
        float vn  = v[(size_t)n*DO + c];
        float s2b = s2[n] - amax;
        int beg = row_start[n], end = row_start[n+1];
        float acc = 0.f, den = 0.f;
        int idx = beg + grp;
        for(; idx + 7*PN < end; idx += 8*PN){
            int sA = sorted_src[idx];
            int sB = sorted_src[idx+PN];
            int sC = sorted_src[idx+2*PN];
            int sD = sorted_src[idx+3*PN];
            int sE = sorted_src[idx+4*PN];
            int sF = sorted_src[idx+5*PN];
            int sG = sorted_src[idx+6*PN];
            int sH = sorted_src[idx+7*PN];
            float aA = s1[sA], aB = s1[sB], aC = s1[sC], aD = s1[sD];
            float aE = s1[sE], aF = s1[sF], aG = s1[sG], aH = s1[sH];
            float uA = u[(size_t)sA*DO+c], uB = u[(size_t)sB*DO+c];
            float uC = u[(size_t)sC*DO+c], uD = u[(size_t)sD*DO+c];
            float uE = u[(size_t)sE*DO+c], uF = u[(size_t)sF*DO+c];
            float uG = u[(size_t)sG*DO+c], uH = u[(size_t)sH*DO+c];
            float pA = __expf(aA + s2b), pB = __expf(aB + s2b);
            float pC = __expf(aC + s2b), pD = __expf(aD + s2b);
            float pE = __expf(aE + s2b), pF = __expf(aF + s2b);
            float pG = __expf(aG + s2b), pH = __expf(aH + s2b);
            den += ((pA+pB)+(pC+pD)) + ((pE+pF)+(pG+pH));
            acc = fmaf(pA, fmaxf(uA+vn+fbc,0.f), acc);
            acc = fmaf(pB, fmaxf(uB+vn+fbc,0.f), acc);
            acc = fmaf(pC, fmaxf(uC+vn+fbc,0.f), acc);
            acc = fmaf(pD, fmaxf(uD+vn+fbc,0.f), acc);
            acc = fmaf(pE, fmaxf(uE+vn+fbc,0.f), acc);
            acc = fmaf(pF, fmaxf(uF+vn+fbc,0.f), acc);
            acc = fmaf(pG, fmaxf(uG+vn+fbc,0.f), acc);
            acc = fmaf(pH, fmaxf(uH+vn+fbc,0.f), acc);
        }
        for(; idx + 3*PN < end; idx += 4*PN){
            int sA = sorted_src[idx];
            int sB = sorted_src[idx+PN];
            int sC = sorted_src[idx+2*PN];
            int sD = sorted_src[idx+3*PN];
            float aA = s1[sA], aB = s1[sB], aC = s1[sC], aD = s1[sD];
            float uA = u[(size_t)sA*DO+c], uB = u[(size_t)sB*DO+c];
            float uC = u[(size_t)sC*DO+c], uD = u[(size_t)sD*DO+c];
            float pA = __expf(aA + s2b), pB = __expf(aB + s2b);
            float pC = __expf(aC + s2b), pD = __expf(aD + s2b);
            den += (pA+pB)+(pC+pD);
            acc = fmaf(pA, fmaxf(uA+vn+fbc,0.f), acc);
            acc = fmaf(pB, fmaxf(uB+vn+fbc,0.f), acc);
            acc = fmaf(pC, fmaxf(uC+vn+fbc,0.f), acc);
            acc = fmaf(pD, fmaxf(uD+vn+fbc,0.f), acc);
        }
        for(; idx < end; idx += PN){
            int s = sorted_src[idx];
            float p = __expf(s1[s] + s2b);
            den += p;
            acc = fmaf(p, fmaxf(u[(size_t)s*DO+c]+vn+fbc,0.f), acc);
        }
        if(PN==2){
            acc += __shfl_xor(acc, 32);
            den += __shfl_xor(den, 32);
        }
        if(lane < DO) xout[(size_t)n*DO + c] = acc / (den + EPSV);
    }
}

// ---------------- graph pooling ----------------
__global__ __launch_bounds__(1024) void k_pool(const float* __restrict__ x, const int* __restrict__ gid,
                        float* __restrict__ g, int N){
    __shared__ float bins[64*64];
    int t = threadIdx.x;
    for(int i=t;i<4096;i+=1024) bins[i]=0.f;
    __syncthreads();
    int lane = t & 63, wid = t>>6;
    int gw = blockIdx.x*16 + wid;
    int nwaves = gridDim.x*16;
    for(int n=gw; n<N; n+=nwaves){
        int gi = gid[n];
        atomicAdd(&bins[gi*64 + lane], x[(size_t)n*64 + lane]);
    }
    __syncthreads();
    for(int i=t;i<4096;i+=1024){
        float b = bins[i];
        if(b != 0.f) atomicAdd(&g[i], b);
    }
}

// ---------------- tiny MLP head ----------------
__global__ __launch_bounds__(1024) void k_mlp(const float* __restrict__ g,
        const float* __restrict__ mw0, const float* __restrict__ mb0,
        const float* __restrict__ mw1, const float* __restrict__ mb1,
        float* __restrict__ out){
    __shared__ float lg[64*64];
    __shared__ float hid[64*32];
    int t = threadIdx.x;
    for(int i=t;i<4096;i+=1024) lg[i]=g[i];
    __syncthreads();
    for(int i=t;i<2048;i+=1024){
        int r = i>>5, h = i&31;
        float a = mb0[h];
        for(int k=0;k<64;k++) a = fmaf(lg[r*64+k], mw0[k*32+h], a);
        hid[i] = fmaxf(a, 0.f);
    }
    __syncthreads();
    for(int i=t;i<640;i+=1024){
        int r = i/10, j = i%10;
        float a = mb1[j];
        for(int h=0;h<32;h++) a = fmaf(hid[r*32+h], mw1[h*10+j], a);
        out[i] = a;
    }
}

extern "C" void kernel_launch(void* const* d_in, const int* in_sizes, int n_in,
                              void* d_out, int out_size, void* d_ws, size_t ws_size,
                              hipStream_t stream){
    const float* x   = (const float*)d_in[0];
    const int*   src = (const int*)d_in[1];
    const int*   tgt = (const int*)d_in[2];
    const int*   gid = (const int*)d_in[3];
    const float* fw[3] = {(const float*)d_in[4],  (const float*)d_in[8],  (const float*)d_in[12]};
    const float* fb[3] = {(const float*)d_in[5],  (const float*)d_in[9],  (const float*)d_in[13]};
    const float* ww[3] = {(const float*)d_in[6],  (const float*)d_in[10], (const float*)d_in[14]};
    const float* mw0 = (const float*)d_in[16];
    const float* mb0 = (const float*)d_in[17];
    const float* mw1 = (const float*)d_in[18];
    const float* mb1 = (const float*)d_in[19];
    float* out = (float*)d_out;

    const int N = in_sizes[3];
    const int E = in_sizes[1];
    const int NB = (N + 255)/256;
    int shift = 0;
    while(((N-1)>>shift) >= 1024) shift++;   // buckets fit in 1024

    char* ws = (char*)d_ws;
    size_t off = 0;
    auto alloc = [&](size_t bytes)->char*{
        char* p = ws + off;
        off += (bytes + 255) & ~(size_t)255;
        return p;
    };
    int*      cnt        = (int*)     alloc((size_t)N*4);
    int*      cursor     = (int*)     alloc((size_t)N*4);
    int*      row_start  = (int*)     alloc((size_t)(N+1)*4);
    int*      sorted_src = (int*)     alloc((size_t)E*4);
    int2*     ebuf       = (int2*)    alloc((size_t)E*8);
    float*    s1         = (float*)   alloc((size_t)N*4);
    float*    s2         = (float*)   alloc((size_t)N*4);
    float*    u          = (float*)   alloc((size_t)N*64*4);
    float*    v          = (float*)   alloc((size_t)N*64*4);
    float*    xA         = (float*)   alloc((size_t)N*64*4);
    float*    xB         = (float*)   alloc((size_t)N*64*4);
    unsigned* amax       = (unsigned*)alloc(6*4);
    float*    g          = (float*)   alloc(4096*4);
    int*      bsum       = (int*)     alloc(512*4);
    int*      bcnt       = (int*)     alloc(1024*4);
    int*      bcur       = (int*)     alloc(1024*4);

    hipMemsetAsync(cnt,  0, (size_t)N*4, stream);
    hipMemsetAsync(amax, 0, 24, stream);
    hipMemsetAsync(g,    0, 4096*4, stream);
    hipMemsetAsync(bcnt, 0, 1024*4, stream);

    k_hist_b <<<512, 256,0,stream>>>(tgt, cnt, bcnt, E, shift);
    k_scan1  <<<NB,  256,0,stream>>>(cnt, bsum, N);
    k_scan2  <<<1,   512,0,stream>>>(bsum, NB);
    k_scan3  <<<NB,  256,0,stream>>>(cnt, bsum, row_start, cursor, N);
    k_bscan  <<<1,  1024,0,stream>>>(bcnt, bcur);
    k_bscat  <<<2048,256,0,stream>>>(src, tgt, bcur, ebuf, E, shift);
    k_nscat  <<<2048,256,0,stream>>>(ebuf, cursor, sorted_src, E);

    // layer 0: 64 -> 32
    k_node_transform_t<64,32><<<NB,256,0,stream>>>(x, fw[0], ww[0], u, v, s1, s2, &amax[0], N);
    k_aggregate_t<32><<<2048,256,0,stream>>>(row_start, sorted_src, u, v, s1, s2, fb[0], &amax[0], xA, N);
    // layer 1: 32 -> 64
    k_node_transform_t<32,64><<<NB,256,0,stream>>>(xA, fw[1], ww[1], u, v, s1, s2, &amax[2], N);
    k_aggregate_t<64><<<2048,256,0,stream>>>(row_start, sorted_src, u, v, s1, s2, fb[1], &amax[2], xB, N);
    // layer 2: 64 -> 64
    k_node_transform_t<64,64><<<NB,256,0,stream>>>(xB, fw[2], ww[2], u, v, s1, s2, &amax[4], N);
    k_aggregate_t<64><<<2048,256,0,stream>>>(row_start, sorted_src, u, v, s1, s2, fb[2], &amax[4], xA, N);

    k_pool<<<128,1024,0,stream>>>(xA, gid, g, N);
    k_mlp <<<1,  1024,0,stream>>>(g, mw0, mb0, mw1, mb1, out);
}

// Round 5
// 689.724 us; speedup vs baseline: 1.4528x; 1.4528x over previous
//
#include <hip/hip_runtime.h>
#include <hip/hip_bf16.h>
#include <math.h>

#define NGRAPH 64
#define EPSV 1e-6f
#define CH 8192          // edges per partition chunk

__device__ __forceinline__ unsigned enc_f32(float f){
    unsigned u = __float_as_uint(f);
    return (u & 0x80000000u) ? ~u : (u | 0x80000000u);
}
__device__ __forceinline__ float dec_f32(unsigned u){
    return (u & 0x80000000u) ? __uint_as_float(u & 0x7FFFFFFFu) : __uint_as_float(~u);
}

// ---------------- CSR build: node hist + per-(chunk,bucket) hist ----------------
__global__ __launch_bounds__(256) void k_hist_c(const int* __restrict__ tgt,
                                                int* __restrict__ cnt,
                                                int* __restrict__ bhist,
                                                int E, int shift, int nbuk){
    __shared__ int h[256];
    int t = threadIdx.x;
    h[t] = 0; __syncthreads();
    int base = blockIdx.x*CH;
    int lim  = base + CH; if(lim > E) lim = E;
    for(int i=base+t; i<lim; i+=256){
        int tt = tgt[i];
        atomicAdd(&cnt[tt], 1);
        atomicAdd(&h[tt>>shift], 1);
    }
    __syncthreads();
    if(t < nbuk) bhist[blockIdx.x*nbuk + t] = h[t];
}

// node-count scans (unchanged)
__global__ __launch_bounds__(256) void k_scan1(const int* __restrict__ cnt, int* __restrict__ bsum, int N){
    __shared__ int red[256];
    int t = threadIdx.x;
    int i = blockIdx.x*256 + t;
    int v = (i<N) ? cnt[i] : 0;
    red[t] = v; __syncthreads();
    for(int off=128; off>0; off>>=1){
        if(t<off) red[t] += red[t+off];
        __syncthreads();
    }
    if(t==0) bsum[blockIdx.x] = red[0];
}

__global__ __launch_bounds__(512) void k_scan2(int* __restrict__ bsum, int nb){
    __shared__ int s[512];
    int t = threadIdx.x;
    int v = (t<nb) ? bsum[t] : 0;
    s[t] = v; __syncthreads();
    for(int off=1; off<512; off<<=1){
        int a = (t>=off) ? s[t-off] : 0;
        __syncthreads();
        s[t] += a;
        __syncthreads();
    }
    if(t<nb) bsum[t] = s[t] - v;
}

__global__ __launch_bounds__(256) void k_scan3(const int* __restrict__ cnt, const int* __restrict__ bsum,
                                               int* __restrict__ row_start, int* __restrict__ cursor, int N){
    __shared__ int s[256];
    int t = threadIdx.x;
    int i = blockIdx.x*256 + t;
    int v = (i<N) ? cnt[i] : 0;
    s[t] = v; __syncthreads();
    for(int off=1; off<256; off<<=1){
        int a = (t>=off) ? s[t-off] : 0;
        __syncthreads();
        s[t] += a;
        __syncthreads();
    }
    int ex = s[t] - v + bsum[blockIdx.x];
    if(i<N){ row_start[i] = ex; cursor[i] = ex; }
    if(i==N-1) row_start[N] = ex + v;
}

// per-bucket totals: one block per bucket, sum over chunks
__global__ __launch_bounds__(256) void k_btot(const int* __restrict__ bhist, int* __restrict__ btot,
                                              int nchunk, int nbuk){
    __shared__ int red[256];
    int b = blockIdx.x, t = threadIdx.x;
    int s = 0;
    for(int blk=t; blk<nchunk; blk+=256) s += bhist[blk*nbuk + b];
    red[t] = s; __syncthreads();
    for(int off=128; off>0; off>>=1){
        if(t<off) red[t] += red[t+off];
        __syncthreads();
    }
    if(t==0) btot[b] = red[0];
}

// exclusive scan of bucket totals
__global__ __launch_bounds__(256) void k_bbase0(const int* __restrict__ btot, int* __restrict__ bbase0, int nbuk){
    __shared__ int s[256];
    int t = threadIdx.x;
    int v = (t<nbuk) ? btot[t] : 0;
    s[t] = v; __syncthreads();
    for(int off=1; off<256; off<<=1){
        int a = (t>=off) ? s[t-off] : 0;
        __syncthreads();
        s[t] += a;
        __syncthreads();
    }
    if(t<nbuk) bbase0[t] = s[t] - v;
}

// per-(chunk,bucket) base = bucket base + prefix over chunks (deterministic, atomic-free)
__global__ __launch_bounds__(256) void k_bbase(const int* __restrict__ bhist, const int* __restrict__ bbase0,
                                               int* __restrict__ bbase, int nchunk, int nbuk){
    __shared__ int s[256];
    int b = blockIdx.x, t = threadIdx.x;
    int v = (t<nchunk) ? bhist[t*nbuk + b] : 0;
    s[t] = v; __syncthreads();
    for(int off=1; off<256; off<<=1){
        int a = (t>=off) ? s[t-off] : 0;
        __syncthreads();
        s[t] += a;
        __syncthreads();
    }
    if(t<nchunk) bbase[t*nbuk + b] = bbase0[b] + s[t] - v;
}

// place edges into bucket-ordered ebuf via LDS tickets; fused exact edge-max for layer 0
__global__ __launch_bounds__(256) void k_place(const int* __restrict__ src, const int* __restrict__ tgt,
                                               const int* __restrict__ bbase, int2* __restrict__ ebuf,
                                               const float* __restrict__ s1, const float* __restrict__ s2,
                                               unsigned* __restrict__ amax_enc,
                                               int E, int shift, int nbuk){
    __shared__ int lcur[256];
    __shared__ float wm[4];
    int t = threadIdx.x, blk = blockIdx.x;
    lcur[t] = (t<nbuk) ? bbase[blk*nbuk + t] : 0;
    __syncthreads();
    int base = blk*CH;
    int lim  = base + CH; if(lim > E) lim = E;
    float m = -3.4e38f;
    for(int i=base+t; i<lim; i+=256){
        int ss = src[i], tt = tgt[i];
        m = fmaxf(m, s1[ss] + s2[tt]);
        int p = atomicAdd(&lcur[tt>>shift], 1);
        ebuf[p] = make_int2(ss, tt);
    }
    for(int off=32; off>0; off>>=1) m = fmaxf(m, __shfl_xor(m, off));
    if((t&63)==0) wm[t>>6] = m;
    __syncthreads();
    if(t==0){
        float mm = fmaxf(fmaxf(wm[0],wm[1]), fmaxf(wm[2],wm[3]));
        atomicMax(amax_enc, enc_f32(mm));
    }
}

// within-bucket node scatter (writes cluster in ~32KB windows; L2-resident)
__global__ __launch_bounds__(256) void k_nscat(const int2* __restrict__ ebuf,
                                               int* __restrict__ cursor, int* __restrict__ sorted_src,
                                               int E){
    int i = blockIdx.x*256 + threadIdx.x;
    int stride = gridDim.x*256;
    for(; i<E; i+=stride){
        int2 e = ebuf[i];
        int pos = atomicAdd(&cursor[e.y], 1);
        sorted_src[pos] = e.x;
    }
}

// ---------------- exact global edge max (layers 1,2) ----------------
__global__ void k_edge_max(const int* __restrict__ src, const int* __restrict__ tgt,
                           const float* __restrict__ s1, const float* __restrict__ s2,
                           unsigned* __restrict__ amax_enc, int E){
    int i = blockIdx.x*blockDim.x + threadIdx.x;
    int stride = gridDim.x*blockDim.x;
    float m = -3.4e38f;
    for(; i<E; i+=stride){
        float a = s1[src[i]] + s2[tgt[i]];
        m = fmaxf(m, a);
    }
    for(int off=32; off>0; off>>=1) m = fmaxf(m, __shfl_xor(m, off));
    if((threadIdx.x & 63)==0) atomicMax(amax_enc, enc_f32(m));
}

// ---------------- per-layer node transform ----------------
template<int DI, int DO>
__global__ __launch_bounds__(256) void k_node_transform_t(
    const float* __restrict__ x, const float* __restrict__ fw,
    const float* __restrict__ ww,
    float* __restrict__ u, float* __restrict__ v,
    float* __restrict__ s1, float* __restrict__ s2, int N)
{
    int n = blockIdx.x*256 + threadIdx.x;
    if(n >= N) return;
    float xr[DI];
    #pragma unroll
    for(int k4=0;k4<DI/4;k4++){
        float4 t = *reinterpret_cast<const float4*>(&x[(size_t)n*DI + k4*4]);
        xr[k4*4+0]=t.x; xr[k4*4+1]=t.y; xr[k4*4+2]=t.z; xr[k4*4+3]=t.w;
    }
    float p1=0.f, p2=0.f;
    #pragma unroll
    for(int k=0;k<DI;k++){
        p1 = fmaf(xr[k], ww[k],    p1);
        p2 = fmaf(xr[k], ww[DI+k], p2);
    }
    s1[n] = p1; s2[n] = p2;
    float acc[DO];
    #pragma unroll
    for(int c=0;c<DO;c++) acc[c]=0.f;
    #pragma unroll
    for(int k=0;k<DI;k++){
        float xk = xr[k];
        #pragma unroll
        for(int c=0;c<DO;c++) acc[c] = fmaf(xk, fw[k*DO+c], acc[c]);
    }
    #pragma unroll
    for(int c4=0;c4<DO/4;c4++)
        *reinterpret_cast<float4*>(&u[(size_t)n*DO + c4*4]) =
            make_float4(acc[c4*4],acc[c4*4+1],acc[c4*4+2],acc[c4*4+3]);
    #pragma unroll
    for(int c=0;c<DO;c++) acc[c]=0.f;
    #pragma unroll
    for(int k=0;k<DI;k++){
        float xk = xr[k];
        #pragma unroll
        for(int c=0;c<DO;c++) acc[c] = fmaf(xk, fw[(DI+k)*DO+c], acc[c]);
    }
    #pragma unroll
    for(int c4=0;c4<DO/4;c4++)
        *reinterpret_cast<float4*>(&v[(size_t)n*DO + c4*4]) =
            make_float4(acc[c4*4],acc[c4*4+1],acc[c4*4+2],acc[c4*4+3]);
}

// ---------------- edge softmax + aggregate (CSR, wave per node) ----------------
template<int DO>
__global__ __launch_bounds__(256) void k_aggregate_t(
    const int* __restrict__ row_start, const int* __restrict__ sorted_src,
    const float* __restrict__ u, const float* __restrict__ v,
    const float* __restrict__ s1, const float* __restrict__ s2,
    const float* __restrict__ fb,
    const unsigned* __restrict__ amax_enc,
    float* __restrict__ xout, int N)
{
    constexpr int PN = 64 / DO;
    float amax = dec_f32(*amax_enc);      // exact max(s1+s2); wb cancels
    int lane = threadIdx.x & 63;
    int wid  = threadIdx.x >> 6;
    int c    = lane & (DO-1);
    int grp  = lane >> (DO==32 ? 5 : 6);
    float fbc = fb[c];
    int gw = blockIdx.x*4 + wid;
    int nwaves = gridDim.x*4;
    for(int n=gw; n<N; n+=nwaves){
        float vn  = v[(size_t)n*DO + c];
        float s2b = s2[n] - amax;
        int beg = row_start[n], end = row_start[n+1];
        float acc = 0.f, den = 0.f;
        int idx = beg + grp;
        for(; idx + 7*PN < end; idx += 8*PN){
            int sA = sorted_src[idx];
            int sB = sorted_src[idx+PN];
            int sC = sorted_src[idx+2*PN];
            int sD = sorted_src[idx+3*PN];
            int sE = sorted_src[idx+4*PN];
            int sF = sorted_src[idx+5*PN];
            int sG = sorted_src[idx+6*PN];
            int sH = sorted_src[idx+7*PN];
            float aA = s1[sA], aB = s1[sB], aC = s1[sC], aD = s1[sD];
            float aE = s1[sE], aF = s1[sF], aG = s1[sG], aH = s1[sH];
            float uA = u[(size_t)sA*DO+c], uB = u[(size_t)sB*DO+c];
            float uC = u[(size_t)sC*DO+c], uD = u[(size_t)sD*DO+c];
            float uE = u[(size_t)sE*DO+c], uF = u[(size_t)sF*DO+c];
            float uG = u[(size_t)sG*DO+c], uH = u[(size_t)sH*DO+c];
            float pA = __expf(aA + s2b), pB = __expf(aB + s2b);
            float pC = __expf(aC + s2b), pD = __expf(aD + s2b);
            float pE = __expf(aE + s2b), pF = __expf(aF + s2b);
            float pG = __expf(aG + s2b), pH = __expf(aH + s2b);
            den += ((pA+pB)+(pC+pD)) + ((pE+pF)+(pG+pH));
            acc = fmaf(pA, fmaxf(uA+vn+fbc,0.f), acc);
            acc = fmaf(pB, fmaxf(uB+vn+fbc,0.f), acc);
            acc = fmaf(pC, fmaxf(uC+vn+fbc,0.f), acc);
            acc = fmaf(pD, fmaxf(uD+vn+fbc,0.f), acc);
            acc = fmaf(pE, fmaxf(uE+vn+fbc,0.f), acc);
            acc = fmaf(pF, fmaxf(uF+vn+fbc,0.f), acc);
            acc = fmaf(pG, fmaxf(uG+vn+fbc,0.f), acc);
            acc = fmaf(pH, fmaxf(uH+vn+fbc,0.f), acc);
        }
        for(; idx + 3*PN < end; idx += 4*PN){
            int sA = sorted_src[idx];
            int sB = sorted_src[idx+PN];
            int sC = sorted_src[idx+2*PN];
            int sD = sorted_src[idx+3*PN];
            float aA = s1[sA], aB = s1[sB], aC = s1[sC], aD = s1[sD];
            float uA = u[(size_t)sA*DO+c], uB = u[(size_t)sB*DO+c];
            float uC = u[(size_t)sC*DO+c], uD = u[(size_t)sD*DO+c];
            float pA = __expf(aA + s2b), pB = __expf(aB + s2b);
            float pC = __expf(aC + s2b), pD = __expf(aD + s2b);
            den += (pA+pB)+(pC+pD);
            acc = fmaf(pA, fmaxf(uA+vn+fbc,0.f), acc);
            acc = fmaf(pB, fmaxf(uB+vn+fbc,0.f), acc);
            acc = fmaf(pC, fmaxf(uC+vn+fbc,0.f), acc);
            acc = fmaf(pD, fmaxf(uD+vn+fbc,0.f), acc);
        }
        for(; idx < end; idx += PN){
            int s = sorted_src[idx];
            float p = __expf(s1[s] + s2b);
            den += p;
            acc = fmaf(p, fmaxf(u[(size_t)s*DO+c]+vn+fbc,0.f), acc);
        }
        if(PN==2){
            acc += __shfl_xor(acc, 32);
            den += __shfl_xor(den, 32);
        }
        if(lane < DO) xout[(size_t)n*DO + c] = acc / (den + EPSV);
    }
}

// ---------------- graph pooling ----------------
__global__ __launch_bounds__(1024) void k_pool(const float* __restrict__ x, const int* __restrict__ gid,
                        float* __restrict__ g, int N){
    __shared__ float bins[64*64];
    int t = threadIdx.x;
    for(int i=t;i<4096;i+=1024) bins[i]=0.f;
    __syncthreads();
    int lane = t & 63, wid = t>>6;
    int gw = blockIdx.x*16 + wid;
    int nwaves = gridDim.x*16;
    for(int n=gw; n<N; n+=nwaves){
        int gi = gid[n];
        atomicAdd(&bins[gi*64 + lane], x[(size_t)n*64 + lane]);
    }
    __syncthreads();
    for(int i=t;i<4096;i+=1024){
        float b = bins[i];
        if(b != 0.f) atomicAdd(&g[i], b);
    }
}

// ---------------- tiny MLP head ----------------
__global__ __launch_bounds__(1024) void k_mlp(const float* __restrict__ g,
        const float* __restrict__ mw0, const float* __restrict__ mb0,
        const float* __restrict__ mw1, const float* __restrict__ mb1,
        float* __restrict__ out){
    __shared__ float lg[64*64];
    __shared__ float hid[64*32];
    int t = threadIdx.x;
    for(int i=t;i<4096;i+=1024) lg[i]=g[i];
    __syncthreads();
    for(int i=t;i<2048;i+=1024){
        int r = i>>5, h = i&31;
        float a = mb0[h];
        for(int k=0;k<64;k++) a = fmaf(lg[r*64+k], mw0[k*32+h], a);
        hid[i] = fmaxf(a, 0.f);
    }
    __syncthreads();
    for(int i=t;i<640;i+=1024){
        int r = i/10, j = i%10;
        float a = mb1[j];
        for(int h=0;h<32;h++) a = fmaf(hid[r*32+h], mw1[h*10+j], a);
        out[i] = a;
    }
}

extern "C" void kernel_launch(void* const* d_in, const int* in_sizes, int n_in,
                              void* d_out, int out_size, void* d_ws, size_t ws_size,
                              hipStream_t stream){
    const float* x   = (const float*)d_in[0];
    const int*   src = (const int*)d_in[1];
    const int*   tgt = (const int*)d_in[2];
    const int*   gid = (const int*)d_in[3];
    const float* fw[3] = {(const float*)d_in[4],  (const float*)d_in[8],  (const float*)d_in[12]};
    const float* fb[3] = {(const float*)d_in[5],  (const float*)d_in[9],  (const float*)d_in[13]};
    const float* ww[3] = {(const float*)d_in[6],  (const float*)d_in[10], (const float*)d_in[14]};
    const float* mw0 = (const float*)d_in[16];
    const float* mb0 = (const float*)d_in[17];
    const float* mw1 = (const float*)d_in[18];
    const float* mb1 = (const float*)d_in[19];
    float* out = (float*)d_out;

    const int N = in_sizes[3];
    const int E = in_sizes[1];
    const int NB = (N + 255)/256;
    const int NCHUNK = (E + CH - 1)/CH;
    int shift = 0;
    while(((N-1)>>shift) >= 256) shift++;   // buckets fit in 256 (196 for N=100K)
    const int nbuk = ((N-1)>>shift) + 1;

    char* ws = (char*)d_ws;
    size_t off = 0;
    auto alloc = [&](size_t bytes)->char*{
        char* p = ws + off;
        off += (bytes + 255) & ~(size_t)255;
        return p;
    };
    int*      cnt        = (int*)     alloc((size_t)N*4);
    int*      cursor     = (int*)     alloc((size_t)N*4);
    int*      row_start  = (int*)     alloc((size_t)(N+1)*4);
    int*      sorted_src = (int*)     alloc((size_t)E*4);
    int2*     ebuf       = (int2*)    alloc((size_t)E*8);
    float*    s1         = (float*)   alloc((size_t)N*4);
    float*    s2         = (float*)   alloc((size_t)N*4);
    float*    u          = (float*)   alloc((size_t)N*64*4);
    float*    v          = (float*)   alloc((size_t)N*64*4);
    float*    xA         = (float*)   alloc((size_t)N*64*4);
    float*    xB         = (float*)   alloc((size_t)N*64*4);
    unsigned* amax       = (unsigned*)alloc(3*4);
    float*    g          = (float*)   alloc(4096*4);
    int*      bsum       = (int*)     alloc(512*4);
    int*      bhist      = (int*)     alloc((size_t)NCHUNK*nbuk*4);
    int*      btot       = (int*)     alloc(256*4);
    int*      bbase0     = (int*)     alloc(256*4);
    int*      bbase      = (int*)     alloc((size_t)NCHUNK*nbuk*4);

    hipMemsetAsync(cnt,  0, (size_t)N*4, stream);
    hipMemsetAsync(amax, 0, 12, stream);
    hipMemsetAsync(g,    0, 4096*4, stream);

    // transform for layer 0 first: s1/s2 ready for fused edge-max in k_place
    k_node_transform_t<64,32><<<NB,256,0,stream>>>(x, fw[0], ww[0], u, v, s1, s2, N);

    k_hist_c <<<NCHUNK,256,0,stream>>>(tgt, cnt, bhist, E, shift, nbuk);
    k_scan1  <<<NB,  256,0,stream>>>(cnt, bsum, N);
    k_scan2  <<<1,   512,0,stream>>>(bsum, NB);
    k_scan3  <<<NB,  256,0,stream>>>(cnt, bsum, row_start, cursor, N);
    k_btot   <<<nbuk,256,0,stream>>>(bhist, btot, NCHUNK, nbuk);
    k_bbase0 <<<1,   256,0,stream>>>(btot, bbase0, nbuk);
    k_bbase  <<<nbuk,256,0,stream>>>(bhist, bbase0, bbase, NCHUNK, nbuk);
    k_place  <<<NCHUNK,256,0,stream>>>(src, tgt, bbase, ebuf, s1, s2, &amax[0], E, shift, nbuk);
    k_nscat  <<<2048,256,0,stream>>>(ebuf, cursor, sorted_src, E);

    // layer 0 aggregate (max already in amax[0])
    k_aggregate_t<32><<<2048,256,0,stream>>>(row_start, sorted_src, u, v, s1, s2, fb[0], &amax[0], xA, N);
    // layer 1: 32 -> 64
    k_node_transform_t<32,64><<<NB,256,0,stream>>>(xA, fw[1], ww[1], u, v, s1, s2, N);
    k_edge_max<<<1024,256,0,stream>>>(src, tgt, s1, s2, &amax[1], E);
    k_aggregate_t<64><<<2048,256,0,stream>>>(row_start, sorted_src, u, v, s1, s2, fb[1], &amax[1], xB, N);
    // layer 2: 64 -> 64
    k_node_transform_t<64,64><<<NB,256,0,stream>>>(xB, fw[2], ww[2], u, v, s1, s2, N);
    k_edge_max<<<1024,256,0,stream>>>(src, tgt, s1, s2, &amax[2], E);
    k_aggregate_t<64><<<2048,256,0,stream>>>(row_start, sorted_src, u, v, s1, s2, fb[2], &amax[2], xA, N);

    k_pool<<<128,1024,0,stream>>>(xA, gid, g, N);
    k_mlp <<<1,  1024,0,stream>>>(g, mw0, mb0, mw1, mb1, out);
}

// Round 6
// 624.698 us; speedup vs baseline: 1.6040x; 1.1041x over previous
//
#include <hip/hip_runtime.h>
#include <hip/hip_bf16.h>
#include <math.h>

#define NGRAPH 64
#define EPSV 1e-6f
#define CH 8192          // edges per partition chunk

__device__ __forceinline__ unsigned enc_f32(float f){
    unsigned u = __float_as_uint(f);
    return (u & 0x80000000u) ? ~u : (u | 0x80000000u);
}
__device__ __forceinline__ float dec_f32(unsigned u){
    return (u & 0x80000000u) ? __uint_as_float(u & 0x7FFFFFFFu) : __uint_as_float(~u);
}

// ---------------- CSR build: node hist + per-(chunk,bucket) hist ----------------
__global__ __launch_bounds__(256) void k_hist_c(const int* __restrict__ tgt,
                                                int* __restrict__ cnt,
                                                int* __restrict__ bhist,
                                                int E, int shift, int nbuk){
    __shared__ int h[256];
    int t = threadIdx.x;
    h[t] = 0; __syncthreads();
    int base = blockIdx.x*CH;
    int lim  = base + CH; if(lim > E) lim = E;
    for(int i=base+t; i<lim; i+=256){
        int tt = tgt[i];
        atomicAdd(&cnt[tt], 1);
        atomicAdd(&h[tt>>shift], 1);
    }
    __syncthreads();
    if(t < nbuk) bhist[blockIdx.x*nbuk + t] = h[t];
}

__global__ __launch_bounds__(256) void k_scan1(const int* __restrict__ cnt, int* __restrict__ bsum, int N){
    __shared__ int red[256];
    int t = threadIdx.x;
    int i = blockIdx.x*256 + t;
    int v = (i<N) ? cnt[i] : 0;
    red[t] = v; __syncthreads();
    for(int off=128; off>0; off>>=1){
        if(t<off) red[t] += red[t+off];
        __syncthreads();
    }
    if(t==0) bsum[blockIdx.x] = red[0];
}

__global__ __launch_bounds__(512) void k_scan2(int* __restrict__ bsum, int nb){
    __shared__ int s[512];
    int t = threadIdx.x;
    int v = (t<nb) ? bsum[t] : 0;
    s[t] = v; __syncthreads();
    for(int off=1; off<512; off<<=1){
        int a = (t>=off) ? s[t-off] : 0;
        __syncthreads();
        s[t] += a;
        __syncthreads();
    }
    if(t<nb) bsum[t] = s[t] - v;
}

__global__ __launch_bounds__(256) void k_scan3(const int* __restrict__ cnt, const int* __restrict__ bsum,
                                               int* __restrict__ row_start, int* __restrict__ cursor, int N){
    __shared__ int s[256];
    int t = threadIdx.x;
    int i = blockIdx.x*256 + t;
    int v = (i<N) ? cnt[i] : 0;
    s[t] = v; __syncthreads();
    for(int off=1; off<256; off<<=1){
        int a = (t>=off) ? s[t-off] : 0;
        __syncthreads();
        s[t] += a;
        __syncthreads();
    }
    int ex = s[t] - v + bsum[blockIdx.x];
    if(i<N){ row_start[i] = ex; cursor[i] = ex; }
    if(i==N-1) row_start[N] = ex + v;
}

__global__ __launch_bounds__(256) void k_btot(const int* __restrict__ bhist, int* __restrict__ btot,
                                              int nchunk, int nbuk){
    __shared__ int red[256];
    int b = blockIdx.x, t = threadIdx.x;
    int s = 0;
    for(int blk=t; blk<nchunk; blk+=256) s += bhist[blk*nbuk + b];
    red[t] = s; __syncthreads();
    for(int off=128; off>0; off>>=1){
        if(t<off) red[t] += red[t+off];
        __syncthreads();
    }
    if(t==0) btot[b] = red[0];
}

__global__ __launch_bounds__(256) void k_bbase0(const int* __restrict__ btot, int* __restrict__ bbase0, int nbuk){
    __shared__ int s[256];
    int t = threadIdx.x;
    int v = (t<nbuk) ? btot[t] : 0;
    s[t] = v; __syncthreads();
    for(int off=1; off<256; off<<=1){
        int a = (t>=off) ? s[t-off] : 0;
        __syncthreads();
        s[t] += a;
        __syncthreads();
    }
    if(t<nbuk) bbase0[t] = s[t] - v;
}

__global__ __launch_bounds__(256) void k_bbase(const int* __restrict__ bhist, const int* __restrict__ bbase0,
                                               int* __restrict__ bbase, int nchunk, int nbuk){
    __shared__ int s[256];
    int b = blockIdx.x, t = threadIdx.x;
    int v = (t<nchunk) ? bhist[t*nbuk + b] : 0;
    s[t] = v; __syncthreads();
    for(int off=1; off<256; off<<=1){
        int a = (t>=off) ? s[t-off] : 0;
        __syncthreads();
        s[t] += a;
        __syncthreads();
    }
    if(t<nchunk) bbase[t*nbuk + b] = bbase0[b] + s[t] - v;
}

// place edges into bucket-ordered ebuf via LDS tickets; fused exact edge-max for layer 0
__global__ __launch_bounds__(256) void k_place(const int* __restrict__ src, const int* __restrict__ tgt,
                                               const int* __restrict__ bbase, int2* __restrict__ ebuf,
                                               const float* __restrict__ s1, const float* __restrict__ s2,
                                               unsigned* __restrict__ amax_enc,
                                               int E, int shift, int nbuk){
    __shared__ int lcur[256];
    __shared__ float wm[4];
    int t = threadIdx.x, blk = blockIdx.x;
    lcur[t] = (t<nbuk) ? bbase[blk*nbuk + t] : 0;
    __syncthreads();
    int base = blk*CH;
    int lim  = base + CH; if(lim > E) lim = E;
    float m = -3.4e38f;
    for(int i=base+t; i<lim; i+=256){
        int ss = src[i], tt = tgt[i];
        m = fmaxf(m, s1[ss] + s2[tt]);
        int p = atomicAdd(&lcur[tt>>shift], 1);
        ebuf[p] = make_int2(ss, tt);
    }
    for(int off=32; off>0; off>>=1) m = fmaxf(m, __shfl_xor(m, off));
    if((t&63)==0) wm[t>>6] = m;
    __syncthreads();
    if(t==0){
        float mm = fmaxf(fmaxf(wm[0],wm[1]), fmaxf(wm[2],wm[3]));
        atomicMax(amax_enc, enc_f32(mm));
    }
}

__global__ __launch_bounds__(256) void k_nscat(const int2* __restrict__ ebuf,
                                               int* __restrict__ cursor, int* __restrict__ sorted_src,
                                               int E){
    int i = blockIdx.x*256 + threadIdx.x;
    int stride = gridDim.x*256;
    for(; i<E; i+=stride){
        int2 e = ebuf[i];
        int pos = atomicAdd(&cursor[e.y], 1);
        sorted_src[pos] = e.x;
    }
}

// ---------------- exact global edge max (layers 1,2) ----------------
__global__ void k_edge_max(const int* __restrict__ src, const int* __restrict__ tgt,
                           const float* __restrict__ s1, const float* __restrict__ s2,
                           unsigned* __restrict__ amax_enc, int E){
    int i = blockIdx.x*blockDim.x + threadIdx.x;
    int stride = gridDim.x*blockDim.x;
    float m = -3.4e38f;
    for(; i<E; i+=stride){
        float a = s1[src[i]] + s2[tgt[i]];
        m = fmaxf(m, a);
    }
    for(int off=32; off>0; off>>=1) m = fmaxf(m, __shfl_xor(m, off));
    if((threadIdx.x & 63)==0) atomicMax(amax_enc, enc_f32(m));
}

// ---------------- node transform: wave = 64 nodes x one 16-col slice ----------------
// lane = node. Weight addresses are wave-uniform (slice from readfirstlane) ->
// scalar-cache s_loads, zero VALU/DS cost. x streamed as float4, consumed
// immediately (low VGPR -> high occupancy). Each lane's 4 float4 stores fill
// exactly one 64B line (no write amplification).
template<int DI, int DO>
__global__ __launch_bounds__(256) void k_xform(
    const float* __restrict__ x, const float* __restrict__ fw,
    const float* __restrict__ ww,
    float* __restrict__ u, float* __restrict__ v,
    float* __restrict__ s1, float* __restrict__ s2, int N)
{
    constexpr int NSLICE = 2*DO/16;       // 16-col slices over [u|v]
    int lane = threadIdx.x & 63;
    int wid  = __builtin_amdgcn_readfirstlane(threadIdx.x >> 6);
    int wg   = blockIdx.x*4 + wid;
    int ngroups = (N+63)>>6;
    if(wg >= ngroups*NSLICE) return;
    int slice = wg % NSLICE;              // adjacent waves share the node group -> L1 reuse of x
    int group = wg / NSLICE;
    int n  = group*64 + lane;
    bool act = n < N;
    int nn = act ? n : N-1;
    bool uhalf = slice < DO/16;
    int scol = (slice & (DO/16 - 1))*16;
    const float* wp  = fw + (uhalf ? 0 : DI*DO) + scol;
    const float* wwp = ww + (uhalf ? 0 : DI);
    float acc[16];
    #pragma unroll
    for(int j=0;j<16;j++) acc[j]=0.f;
    float p = 0.f;
    #pragma unroll
    for(int k4=0;k4<DI/4;k4++){
        float4 xv = *reinterpret_cast<const float4*>(&x[(size_t)nn*DI + k4*4]);
        #pragma unroll
        for(int kk=0;kk<4;kk++){
            float xk = (kk==0)?xv.x:(kk==1)?xv.y:(kk==2)?xv.z:xv.w;
            int k = k4*4+kk;
            p = fmaf(xk, wwp[k], p);
            #pragma unroll
            for(int j=0;j<16;j++) acc[j] = fmaf(xk, wp[k*DO + j], acc[j]);
        }
    }
    if(act){
        float* outp = uhalf ? u : v;
        #pragma unroll
        for(int j4=0;j4<4;j4++)
            *reinterpret_cast<float4*>(&outp[(size_t)n*DO + scol + j4*4]) =
                make_float4(acc[j4*4],acc[j4*4+1],acc[j4*4+2],acc[j4*4+3]);
        if(scol==0) (uhalf ? s1 : s2)[n] = p;
    }
}

// ---------------- edge softmax + aggregate (CSR, wave per node) ----------------
template<int DO>
__global__ __launch_bounds__(256) void k_aggregate_t(
    const int* __restrict__ row_start, const int* __restrict__ sorted_src,
    const float* __restrict__ u, const float* __restrict__ v,
    const float* __restrict__ s1, const float* __restrict__ s2,
    const float* __restrict__ fb,
    const unsigned* __restrict__ amax_enc,
    float* __restrict__ xout, int N)
{
    constexpr int PN = 64 / DO;
    float amax = dec_f32(*amax_enc);      // exact max(s1+s2); wb cancels
    int lane = threadIdx.x & 63;
    int wid  = threadIdx.x >> 6;
    int c    = lane & (DO-1);
    int grp  = lane >> (DO==32 ? 5 : 6);
    float fbc = fb[c];
    int gw = blockIdx.x*4 + wid;
    int nwaves = gridDim.x*4;
    for(int n=gw; n<N; n+=nwaves){
        float vn  = v[(size_t)n*DO + c];
        float s2b = s2[n] - amax;
        int beg = row_start[n], end = row_start[n+1];
        float acc = 0.f, den = 0.f;
        int idx = beg + grp;
        for(; idx + 7*PN < end; idx += 8*PN){
            int sA = sorted_src[idx];
            int sB = sorted_src[idx+PN];
            int sC = sorted_src[idx+2*PN];
            int sD = sorted_src[idx+3*PN];
            int sE = sorted_src[idx+4*PN];
            int sF = sorted_src[idx+5*PN];
            int sG = sorted_src[idx+6*PN];
            int sH = sorted_src[idx+7*PN];
            float aA = s1[sA], aB = s1[sB], aC = s1[sC], aD = s1[sD];
            float aE = s1[sE], aF = s1[sF], aG = s1[sG], aH = s1[sH];
            float uA = u[(size_t)sA*DO+c], uB = u[(size_t)sB*DO+c];
            float uC = u[(size_t)sC*DO+c], uD = u[(size_t)sD*DO+c];
            float uE = u[(size_t)sE*DO+c], uF = u[(size_t)sF*DO+c];
            float uG = u[(size_t)sG*DO+c], uH = u[(size_t)sH*DO+c];
            float pA = __expf(aA + s2b), pB = __expf(aB + s2b);
            float pC = __expf(aC + s2b), pD = __expf(aD + s2b);
            float pE = __expf(aE + s2b), pF = __expf(aF + s2b);
            float pG = __expf(aG + s2b), pH = __expf(aH + s2b);
            den += ((pA+pB)+(pC+pD)) + ((pE+pF)+(pG+pH));
            acc = fmaf(pA, fmaxf(uA+vn+fbc,0.f), acc);
            acc = fmaf(pB, fmaxf(uB+vn+fbc,0.f), acc);
            acc = fmaf(pC, fmaxf(uC+vn+fbc,0.f), acc);
            acc = fmaf(pD, fmaxf(uD+vn+fbc,0.f), acc);
            acc = fmaf(pE, fmaxf(uE+vn+fbc,0.f), acc);
            acc = fmaf(pF, fmaxf(uF+vn+fbc,0.f), acc);
            acc = fmaf(pG, fmaxf(uG+vn+fbc,0.f), acc);
            acc = fmaf(pH, fmaxf(uH+vn+fbc,0.f), acc);
        }
        for(; idx + 3*PN < end; idx += 4*PN){
            int sA = sorted_src[idx];
            int sB = sorted_src[idx+PN];
            int sC = sorted_src[idx+2*PN];
            int sD = sorted_src[idx+3*PN];
            float aA = s1[sA], aB = s1[sB], aC = s1[sC], aD = s1[sD];
            float uA = u[(size_t)sA*DO+c], uB = u[(size_t)sB*DO+c];
            float uC = u[(size_t)sC*DO+c], uD = u[(size_t)sD*DO+c];
            float pA = __expf(aA + s2b), pB = __expf(aB + s2b);
            float pC = __expf(aC + s2b), pD = __expf(aD + s2b);
            den += (pA+pB)+(pC+pD);
            acc = fmaf(pA, fmaxf(uA+vn+fbc,0.f), acc);
            acc = fmaf(pB, fmaxf(uB+vn+fbc,0.f), acc);
            acc = fmaf(pC, fmaxf(uC+vn+fbc,0.f), acc);
            acc = fmaf(pD, fmaxf(uD+vn+fbc,0.f), acc);
        }
        for(; idx < end; idx += PN){
            int s = sorted_src[idx];
            float p = __expf(s1[s] + s2b);
            den += p;
            acc = fmaf(p, fmaxf(u[(size_t)s*DO+c]+vn+fbc,0.f), acc);
        }
        if(PN==2){
            acc += __shfl_xor(acc, 32);
            den += __shfl_xor(den, 32);
        }
        if(lane < DO) xout[(size_t)n*DO + c] = acc / (den + EPSV);
    }
}

// ---------------- graph pooling ----------------
__global__ __launch_bounds__(1024) void k_pool(const float* __restrict__ x, const int* __restrict__ gid,
                        float* __restrict__ g, int N){
    __shared__ float bins[64*64];
    int t = threadIdx.x;
    for(int i=t;i<4096;i+=1024) bins[i]=0.f;
    __syncthreads();
    int lane = t & 63, wid = t>>6;
    int gw = blockIdx.x*16 + wid;
    int nwaves = gridDim.x*16;
    for(int n=gw; n<N; n+=nwaves){
        int gi = gid[n];
        atomicAdd(&bins[gi*64 + lane], x[(size_t)n*64 + lane]);
    }
    __syncthreads();
    for(int i=t;i<4096;i+=1024){
        float b = bins[i];
        if(b != 0.f) atomicAdd(&g[i], b);
    }
}

// ---------------- tiny MLP head ----------------
__global__ __launch_bounds__(1024) void k_mlp(const float* __restrict__ g,
        const float* __restrict__ mw0, const float* __restrict__ mb0,
        const float* __restrict__ mw1, const float* __restrict__ mb1,
        float* __restrict__ out){
    __shared__ float lg[64*64];
    __shared__ float hid[64*32];
    int t = threadIdx.x;
    for(int i=t;i<4096;i+=1024) lg[i]=g[i];
    __syncthreads();
    for(int i=t;i<2048;i+=1024){
        int r = i>>5, h = i&31;
        float a = mb0[h];
        for(int k=0;k<64;k++) a = fmaf(lg[r*64+k], mw0[k*32+h], a);
        hid[i] = fmaxf(a, 0.f);
    }
    __syncthreads();
    for(int i=t;i<640;i+=1024){
        int r = i/10, j = i%10;
        float a = mb1[j];
        for(int h=0;h<32;h++) a = fmaf(hid[r*32+h], mw1[h*10+j], a);
        out[i] = a;
    }
}

extern "C" void kernel_launch(void* const* d_in, const int* in_sizes, int n_in,
                              void* d_out, int out_size, void* d_ws, size_t ws_size,
                              hipStream_t stream){
    const float* x   = (const float*)d_in[0];
    const int*   src = (const int*)d_in[1];
    const int*   tgt = (const int*)d_in[2];
    const int*   gid = (const int*)d_in[3];
    const float* fw[3] = {(const float*)d_in[4],  (const float*)d_in[8],  (const float*)d_in[12]};
    const float* fb[3] = {(const float*)d_in[5],  (const float*)d_in[9],  (const float*)d_in[13]};
    const float* ww[3] = {(const float*)d_in[6],  (const float*)d_in[10], (const float*)d_in[14]};
    const float* mw0 = (const float*)d_in[16];
    const float* mb0 = (const float*)d_in[17];
    const float* mw1 = (const float*)d_in[18];
    const float* mb1 = (const float*)d_in[19];
    float* out = (float*)d_out;

    const int N = in_sizes[3];
    const int E = in_sizes[1];
    const int NB = (N + 255)/256;
    const int NG = (N + 63)/64;          // node groups of 64
    const int NCHUNK = (E + CH - 1)/CH;
    int shift = 0;
    while(((N-1)>>shift) >= 256) shift++;
    const int nbuk = ((N-1)>>shift) + 1;

    char* ws = (char*)d_ws;
    size_t off = 0;
    auto alloc = [&](size_t bytes)->char*{
        char* p = ws + off;
        off += (bytes + 255) & ~(size_t)255;
        return p;
    };
    int*      cnt        = (int*)     alloc((size_t)N*4);
    int*      cursor     = (int*)     alloc((size_t)N*4);
    int*      row_start  = (int*)     alloc((size_t)(N+1)*4);
    int*      sorted_src = (int*)     alloc((size_t)E*4);
    int2*     ebuf       = (int2*)    alloc((size_t)E*8);
    float*    s1         = (float*)   alloc((size_t)N*4);
    float*    s2         = (float*)   alloc((size_t)N*4);
    float*    u          = (float*)   alloc((size_t)N*64*4);
    float*    v          = (float*)   alloc((size_t)N*64*4);
    float*    xA         = (float*)   alloc((size_t)N*64*4);
    float*    xB         = (float*)   alloc((size_t)N*64*4);
    unsigned* amax       = (unsigned*)alloc(3*4);
    float*    g          = (float*)   alloc(4096*4);
    int*      bsum       = (int*)     alloc(512*4);
    int*      bhist      = (int*)     alloc((size_t)NCHUNK*nbuk*4);
    int*      btot       = (int*)     alloc(256*4);
    int*      bbase0     = (int*)     alloc(256*4);
    int*      bbase      = (int*)     alloc((size_t)NCHUNK*nbuk*4);

    hipMemsetAsync(cnt,  0, (size_t)N*4, stream);
    hipMemsetAsync(amax, 0, 12, stream);
    hipMemsetAsync(g,    0, 4096*4, stream);

    // transform for layer 0 first: s1/s2 ready for fused edge-max in k_place
    k_xform<64,32><<<(NG*4+3)/4,256,0,stream>>>(x, fw[0], ww[0], u, v, s1, s2, N);

    k_hist_c <<<NCHUNK,256,0,stream>>>(tgt, cnt, bhist, E, shift, nbuk);
    k_scan1  <<<NB,  256,0,stream>>>(cnt, bsum, N);
    k_scan2  <<<1,   512,0,stream>>>(bsum, NB);
    k_scan3  <<<NB,  256,0,stream>>>(cnt, bsum, row_start, cursor, N);
    k_btot   <<<nbuk,256,0,stream>>>(bhist, btot, NCHUNK, nbuk);
    k_bbase0 <<<1,   256,0,stream>>>(btot, bbase0, nbuk);
    k_bbase  <<<nbuk,256,0,stream>>>(bhist, bbase0, bbase, NCHUNK, nbuk);
    k_place  <<<NCHUNK,256,0,stream>>>(src, tgt, bbase, ebuf, s1, s2, &amax[0], E, shift, nbuk);
    k_nscat  <<<2048,256,0,stream>>>(ebuf, cursor, sorted_src, E);

    // layer 0 aggregate (max already in amax[0])
    k_aggregate_t<32><<<2048,256,0,stream>>>(row_start, sorted_src, u, v, s1, s2, fb[0], &amax[0], xA, N);
    // layer 1: 32 -> 64
    k_xform<32,64><<<(NG*8+3)/4,256,0,stream>>>(xA, fw[1], ww[1], u, v, s1, s2, N);
    k_edge_max<<<1024,256,0,stream>>>(src, tgt, s1, s2, &amax[1], E);
    k_aggregate_t<64><<<2048,256,0,stream>>>(row_start, sorted_src, u, v, s1, s2, fb[1], &amax[1], xB, N);
    // layer 2: 64 -> 64
    k_xform<64,64><<<(NG*8+3)/4,256,0,stream>>>(xB, fw[2], ww[2], u, v, s1, s2, N);
    k_edge_max<<<1024,256,0,stream>>>(src, tgt, s1, s2, &amax[2], E);
    k_aggregate_t<64><<<2048,256,0,stream>>>(row_start, sorted_src, u, v, s1, s2, fb[2], &amax[2], xA, N);

    k_pool<<<128,1024,0,stream>>>(xA, gid, g, N);
    k_mlp <<<1,  1024,0,stream>>>(g, mw0, mb0, mw1, mb1, out);
}

// Round 7
// 606.543 us; speedup vs baseline: 1.6520x; 1.0299x over previous
//
#include <hip/hip_runtime.h>
#include <hip/hip_bf16.h>
#include <math.h>

#define NGRAPH 64
#define EPSV 1e-6f
#define CH 8192          // edges per partition chunk

__device__ __forceinline__ unsigned enc_f32(float f){
    unsigned u = __float_as_uint(f);
    return (u & 0x80000000u) ? ~u : (u | 0x80000000u);
}
__device__ __forceinline__ float dec_f32(unsigned u){
    return (u & 0x80000000u) ? __uint_as_float(u & 0x7FFFFFFFu) : __uint_as_float(~u);
}
__device__ __forceinline__ unsigned bf16_rn(float x){   // f32 -> bf16 bits (RNE)
    unsigned u = __float_as_uint(x);
    return (u + 0x7fffu + ((u>>16)&1u)) >> 16;
}
__device__ __forceinline__ float bflo(unsigned u){ return __uint_as_float(u<<16); }
__device__ __forceinline__ float bfhi(unsigned u){ return __uint_as_float(u & 0xffff0000u); }

// ---------------- CSR build: node hist + per-(chunk,bucket) hist ----------------
__global__ __launch_bounds__(256) void k_hist_c(const int* __restrict__ tgt,
                                                int* __restrict__ cnt,
                                                int* __restrict__ bhist,
                                                int E, int shift, int nbuk){
    __shared__ int h[256];
    int t = threadIdx.x;
    h[t] = 0; __syncthreads();
    int base = blockIdx.x*CH;
    int lim  = base + CH; if(lim > E) lim = E;
    for(int i=base+t; i<lim; i+=256){
        int tt = tgt[i];
        atomicAdd(&cnt[tt], 1);
        atomicAdd(&h[tt>>shift], 1);
    }
    __syncthreads();
    if(t < nbuk) bhist[blockIdx.x*nbuk + t] = h[t];
}

__global__ __launch_bounds__(256) void k_scan1(const int* __restrict__ cnt, int* __restrict__ bsum, int N){
    __shared__ int red[256];
    int t = threadIdx.x;
    int i = blockIdx.x*256 + t;
    int v = (i<N) ? cnt[i] : 0;
    red[t] = v; __syncthreads();
    for(int off=128; off>0; off>>=1){
        if(t<off) red[t] += red[t+off];
        __syncthreads();
    }
    if(t==0) bsum[blockIdx.x] = red[0];
}

__global__ __launch_bounds__(512) void k_scan2(int* __restrict__ bsum, int nb){
    __shared__ int s[512];
    int t = threadIdx.x;
    int v = (t<nb) ? bsum[t] : 0;
    s[t] = v; __syncthreads();
    for(int off=1; off<512; off<<=1){
        int a = (t>=off) ? s[t-off] : 0;
        __syncthreads();
        s[t] += a;
        __syncthreads();
    }
    if(t<nb) bsum[t] = s[t] - v;
}

__global__ __launch_bounds__(256) void k_scan3(const int* __restrict__ cnt, const int* __restrict__ bsum,
                                               int* __restrict__ row_start, int* __restrict__ cursor, int N){
    __shared__ int s[256];
    int t = threadIdx.x;
    int i = blockIdx.x*256 + t;
    int v = (i<N) ? cnt[i] : 0;
    s[t] = v; __syncthreads();
    for(int off=1; off<256; off<<=1){
        int a = (t>=off) ? s[t-off] : 0;
        __syncthreads();
        s[t] += a;
        __syncthreads();
    }
    int ex = s[t] - v + bsum[blockIdx.x];
    if(i<N){ row_start[i] = ex; cursor[i] = ex; }
    if(i==N-1) row_start[N] = ex + v;
}

__global__ __launch_bounds__(256) void k_btot(const int* __restrict__ bhist, int* __restrict__ btot,
                                              int nchunk, int nbuk){
    __shared__ int red[256];
    int b = blockIdx.x, t = threadIdx.x;
    int s = 0;
    for(int blk=t; blk<nchunk; blk+=256) s += bhist[blk*nbuk + b];
    red[t] = s; __syncthreads();
    for(int off=128; off>0; off>>=1){
        if(t<off) red[t] += red[t+off];
        __syncthreads();
    }
    if(t==0) btot[b] = red[0];
}

__global__ __launch_bounds__(256) void k_bbase0(const int* __restrict__ btot, int* __restrict__ bbase0, int nbuk){
    __shared__ int s[256];
    int t = threadIdx.x;
    int v = (t<nbuk) ? btot[t] : 0;
    s[t] = v; __syncthreads();
    for(int off=1; off<256; off<<=1){
        int a = (t>=off) ? s[t-off] : 0;
        __syncthreads();
        s[t] += a;
        __syncthreads();
    }
    if(t<nbuk) bbase0[t] = s[t] - v;
}

__global__ __launch_bounds__(256) void k_bbase(const int* __restrict__ bhist, const int* __restrict__ bbase0,
                                               int* __restrict__ bbase, int nchunk, int nbuk){
    __shared__ int s[256];
    int b = blockIdx.x, t = threadIdx.x;
    int v = (t<nchunk) ? bhist[t*nbuk + b] : 0;
    s[t] = v; __syncthreads();
    for(int off=1; off<256; off<<=1){
        int a = (t>=off) ? s[t-off] : 0;
        __syncthreads();
        s[t] += a;
        __syncthreads();
    }
    if(t<nchunk) bbase[t*nbuk + b] = bbase0[b] + s[t] - v;
}

// place edges into bucket-ordered ebuf via LDS tickets; fused exact edge-max for layer 0
__global__ __launch_bounds__(256) void k_place(const int* __restrict__ src, const int* __restrict__ tgt,
                                               const int* __restrict__ bbase, int2* __restrict__ ebuf,
                                               const float* __restrict__ s1, const float* __restrict__ s2,
                                               unsigned* __restrict__ amax_enc,
                                               int E, int shift, int nbuk){
    __shared__ int lcur[256];
    __shared__ float wm[4];
    int t = threadIdx.x, blk = blockIdx.x;
    lcur[t] = (t<nbuk) ? bbase[blk*nbuk + t] : 0;
    __syncthreads();
    int base = blk*CH;
    int lim  = base + CH; if(lim > E) lim = E;
    float m = -3.4e38f;
    for(int i=base+t; i<lim; i+=256){
        int ss = src[i], tt = tgt[i];
        m = fmaxf(m, s1[ss] + s2[tt]);
        int p = atomicAdd(&lcur[tt>>shift], 1);
        ebuf[p] = make_int2(ss, tt);
    }
    for(int off=32; off>0; off>>=1) m = fmaxf(m, __shfl_xor(m, off));
    if((t&63)==0) wm[t>>6] = m;
    __syncthreads();
    if(t==0){
        float mm = fmaxf(fmaxf(wm[0],wm[1]), fmaxf(wm[2],wm[3]));
        atomicMax(amax_enc, enc_f32(mm));
    }
}

__global__ __launch_bounds__(256) void k_nscat(const int2* __restrict__ ebuf,
                                               int* __restrict__ cursor, int* __restrict__ sorted_src,
                                               int E){
    int i = blockIdx.x*256 + threadIdx.x;
    int stride = gridDim.x*256;
    for(; i<E; i+=stride){
        int2 e = ebuf[i];
        int pos = atomicAdd(&cursor[e.y], 1);
        sorted_src[pos] = e.x;
    }
}

// ---------------- exact global edge max (layers 1,2), x4 unrolled ----------------
__global__ __launch_bounds__(256) void k_edge_max(const int* __restrict__ src, const int* __restrict__ tgt,
                           const float* __restrict__ s1, const float* __restrict__ s2,
                           unsigned* __restrict__ amax_enc, int E){
    int i4 = (blockIdx.x*256 + threadIdx.x)*4;
    int stride = gridDim.x*256*4;
    float m = -3.4e38f;
    for(; i4+3 < E; i4 += stride){
        int4 s4 = *reinterpret_cast<const int4*>(&src[i4]);
        int4 t4 = *reinterpret_cast<const int4*>(&tgt[i4]);
        float a0 = s1[s4.x]+s2[t4.x], a1 = s1[s4.y]+s2[t4.y];
        float a2 = s1[s4.z]+s2[t4.z], a3 = s1[s4.w]+s2[t4.w];
        m = fmaxf(m, fmaxf(fmaxf(a0,a1), fmaxf(a2,a3)));
    }
    for(; i4 < E; i4++) m = fmaxf(m, s1[src[i4]] + s2[tgt[i4]]);
    for(int off=32; off>0; off>>=1) m = fmaxf(m, __shfl_xor(m, off));
    if((threadIdx.x & 63)==0) atomicMax(amax_enc, enc_f32(m));
}

// e1 = exp(s1 - amax), e2 = exp(s2), in place
__global__ __launch_bounds__(256) void k_prep(float* __restrict__ s1, float* __restrict__ s2,
                                              const unsigned* __restrict__ amax_enc, int N){
    int n = blockIdx.x*256 + threadIdx.x;
    if(n >= N) return;
    float amax = dec_f32(*amax_enc);
    s1[n] = __expf(s1[n] - amax);
    s2[n] = __expf(s2[n]);
}

// ---------------- node transform: wave = 64 nodes x one 16-col slice ----------------
// u written as packed bf16 (halves edge-gather traffic); v stays fp32.
template<int DI, int DO>
__global__ __launch_bounds__(256) void k_xform(
    const float* __restrict__ x, const float* __restrict__ fw,
    const float* __restrict__ ww,
    unsigned* __restrict__ ubf, float* __restrict__ v,
    float* __restrict__ s1, float* __restrict__ s2, int N)
{
    constexpr int NSLICE = 2*DO/16;
    constexpr int CP = DO/2;              // ubf row stride in uints
    int lane = threadIdx.x & 63;
    int wid  = __builtin_amdgcn_readfirstlane(threadIdx.x >> 6);
    int wg   = blockIdx.x*4 + wid;
    int ngroups = (N+63)>>6;
    if(wg >= ngroups*NSLICE) return;
    int slice = wg % NSLICE;
    int group = wg / NSLICE;
    int n  = group*64 + lane;
    bool act = n < N;
    int nn = act ? n : N-1;
    bool uhalf = slice < DO/16;
    int scol = (slice & (DO/16 - 1))*16;
    const float* wp  = fw + (uhalf ? 0 : DI*DO) + scol;
    const float* wwp = ww + (uhalf ? 0 : DI);
    float acc[16];
    #pragma unroll
    for(int j=0;j<16;j++) acc[j]=0.f;
    float p = 0.f;
    #pragma unroll
    for(int k4=0;k4<DI/4;k4++){
        float4 xv = *reinterpret_cast<const float4*>(&x[(size_t)nn*DI + k4*4]);
        #pragma unroll
        for(int kk=0;kk<4;kk++){
            float xk = (kk==0)?xv.x:(kk==1)?xv.y:(kk==2)?xv.z:xv.w;
            int k = k4*4+kk;
            p = fmaf(xk, wwp[k], p);
            #pragma unroll
            for(int j=0;j<16;j++) acc[j] = fmaf(xk, wp[k*DO + j], acc[j]);
        }
    }
    if(act){
        if(uhalf){
            unsigned pk[8];
            #pragma unroll
            for(int j=0;j<8;j++)
                pk[j] = bf16_rn(acc[2*j]) | (bf16_rn(acc[2*j+1])<<16);
            unsigned* dst = &ubf[(size_t)n*CP + scol/2];
            *reinterpret_cast<uint4*>(dst)   = make_uint4(pk[0],pk[1],pk[2],pk[3]);
            *reinterpret_cast<uint4*>(dst+4) = make_uint4(pk[4],pk[5],pk[6],pk[7]);
        } else {
            #pragma unroll
            for(int j4=0;j4<4;j4++)
                *reinterpret_cast<float4*>(&v[(size_t)n*DO + scol + j4*4]) =
                    make_float4(acc[j4*4],acc[j4*4+1],acc[j4*4+2],acc[j4*4+3]);
        }
        if(scol==0) (uhalf ? s1 : s2)[n] = p;
    }
}

// ---------------- edge softmax + aggregate: lane = channel PAIR ----------------
// CP=DO/2 lanes per edge, PN=64/CP edge groups per wave. u gathers are bf16x2
// (4B/lane, 128B/row for DO=64). p = e1[src]*e2[tgt] (exp hoisted to k_prep).
template<int DO>
__global__ __launch_bounds__(256) void k_aggregate2(
    const int* __restrict__ row_start, const int* __restrict__ sorted_src,
    const unsigned* __restrict__ ubf, const float* __restrict__ v,
    const float* __restrict__ e1, const float* __restrict__ e2,
    const float* __restrict__ fb,
    float* __restrict__ xout, int N)
{
    constexpr int CP = DO/2;
    constexpr int PN = 64/CP;
    int lane = threadIdx.x & 63;
    int wid  = threadIdx.x >> 6;
    int c2   = lane & (CP-1);
    int grp  = lane >> (CP==32 ? 5 : 4);
    float fx = fb[2*c2], fy = fb[2*c2+1];
    int gw = blockIdx.x*4 + wid;
    int nwaves = gridDim.x*4;
    for(int n=gw; n<N; n+=nwaves){
        float2 vv = *reinterpret_cast<const float2*>(&v[(size_t)n*DO + 2*c2]);
        float wx = vv.x + fx, wy = vv.y + fy;
        float e2n = e2[n];
        int beg = row_start[n], end = row_start[n+1];
        float ax = 0.f, ay = 0.f, den = 0.f;
        int idx = beg + grp;
        for(; idx + 3*PN < end; idx += 4*PN){
            int sA = sorted_src[idx];
            int sB = sorted_src[idx+PN];
            int sC = sorted_src[idx+2*PN];
            int sD = sorted_src[idx+3*PN];
            float eA = e1[sA], eB = e1[sB], eC = e1[sC], eD = e1[sD];
            unsigned uA = ubf[(size_t)sA*CP+c2], uB = ubf[(size_t)sB*CP+c2];
            unsigned uC = ubf[(size_t)sC*CP+c2], uD = ubf[(size_t)sD*CP+c2];
            float pA = eA*e2n, pB = eB*e2n, pC = eC*e2n, pD = eD*e2n;
            den += (pA+pB)+(pC+pD);
            ax = fmaf(pA, fmaxf(bflo(uA)+wx,0.f), ax);
            ay = fmaf(pA, fmaxf(bfhi(uA)+wy,0.f), ay);
            ax = fmaf(pB, fmaxf(bflo(uB)+wx,0.f), ax);
            ay = fmaf(pB, fmaxf(bfhi(uB)+wy,0.f), ay);
            ax = fmaf(pC, fmaxf(bflo(uC)+wx,0.f), ax);
            ay = fmaf(pC, fmaxf(bfhi(uC)+wy,0.f), ay);
            ax = fmaf(pD, fmaxf(bflo(uD)+wx,0.f), ax);
            ay = fmaf(pD, fmaxf(bfhi(uD)+wy,0.f), ay);
        }
        for(; idx < end; idx += PN){
            int s = sorted_src[idx];
            float e = e1[s];
            unsigned uu = ubf[(size_t)s*CP+c2];
            float p = e*e2n;
            den += p;
            ax = fmaf(p, fmaxf(bflo(uu)+wx,0.f), ax);
            ay = fmaf(p, fmaxf(bfhi(uu)+wy,0.f), ay);
        }
        #pragma unroll
        for(int off=CP; off<64; off<<=1){
            den += __shfl_xor(den, off);
            ax  += __shfl_xor(ax , off);
            ay  += __shfl_xor(ay , off);
        }
        if(lane < CP){
            float d = den + EPSV;
            *reinterpret_cast<float2*>(&xout[(size_t)n*DO + 2*c2]) =
                make_float2(ax/d, ay/d);
        }
    }
}

// ---------------- graph pooling ----------------
__global__ __launch_bounds__(1024) void k_pool(const float* __restrict__ x, const int* __restrict__ gid,
                        float* __restrict__ g, int N){
    __shared__ float bins[64*64];
    int t = threadIdx.x;
    for(int i=t;i<4096;i+=1024) bins[i]=0.f;
    __syncthreads();
    int lane = t & 63, wid = t>>6;
    int gw = blockIdx.x*16 + wid;
    int nwaves = gridDim.x*16;
    for(int n=gw; n<N; n+=nwaves){
        int gi = gid[n];
        atomicAdd(&bins[gi*64 + lane], x[(size_t)n*64 + lane]);
    }
    __syncthreads();
    for(int i=t;i<4096;i+=1024){
        float b = bins[i];
        if(b != 0.f) atomicAdd(&g[i], b);
    }
}

// ---------------- tiny MLP head ----------------
__global__ __launch_bounds__(1024) void k_mlp(const float* __restrict__ g,
        const float* __restrict__ mw0, const float* __restrict__ mb0,
        const float* __restrict__ mw1, const float* __restrict__ mb1,
        float* __restrict__ out){
    __shared__ float lg[64*64];
    __shared__ float hid[64*32];
    int t = threadIdx.x;
    for(int i=t;i<4096;i+=1024) lg[i]=g[i];
    __syncthreads();
    for(int i=t;i<2048;i+=1024){
        int r = i>>5, h = i&31;
        float a = mb0[h];
        for(int k=0;k<64;k++) a = fmaf(lg[r*64+k], mw0[k*32+h], a);
        hid[i] = fmaxf(a, 0.f);
    }
    __syncthreads();
    for(int i=t;i<640;i+=1024){
        int r = i/10, j = i%10;
        float a = mb1[j];
        for(int h=0;h<32;h++) a = fmaf(hid[r*32+h], mw1[h*10+j], a);
        out[i] = a;
    }
}

extern "C" void kernel_launch(void* const* d_in, const int* in_sizes, int n_in,
                              void* d_out, int out_size, void* d_ws, size_t ws_size,
                              hipStream_t stream){
    const float* x   = (const float*)d_in[0];
    const int*   src = (const int*)d_in[1];
    const int*   tgt = (const int*)d_in[2];
    const int*   gid = (const int*)d_in[3];
    const float* fw[3] = {(const float*)d_in[4],  (const float*)d_in[8],  (const float*)d_in[12]};
    const float* fb[3] = {(const float*)d_in[5],  (const float*)d_in[9],  (const float*)d_in[13]};
    const float* ww[3] = {(const float*)d_in[6],  (const float*)d_in[10], (const float*)d_in[14]};
    const float* mw0 = (const float*)d_in[16];
    const float* mb0 = (const float*)d_in[17];
    const float* mw1 = (const float*)d_in[18];
    const float* mb1 = (const float*)d_in[19];
    float* out = (float*)d_out;

    const int N = in_sizes[3];
    const int E = in_sizes[1];
    const int NB = (N + 255)/256;
    const int NG = (N + 63)/64;
    const int NCHUNK = (E + CH - 1)/CH;
    int shift = 0;
    while(((N-1)>>shift) >= 256) shift++;
    const int nbuk = ((N-1)>>shift) + 1;

    char* ws = (char*)d_ws;
    size_t off = 0;
    auto alloc = [&](size_t bytes)->char*{
        char* p = ws + off;
        off += (bytes + 255) & ~(size_t)255;
        return p;
    };
    int*      cnt        = (int*)     alloc((size_t)N*4);
    int*      cursor     = (int*)     alloc((size_t)N*4);
    int*      row_start  = (int*)     alloc((size_t)(N+1)*4);
    int*      sorted_src = (int*)     alloc((size_t)E*4);
    int2*     ebuf       = (int2*)    alloc((size_t)E*8);
    float*    s1         = (float*)   alloc((size_t)N*4);
    float*    s2         = (float*)   alloc((size_t)N*4);
    unsigned* ubf        = (unsigned*)alloc((size_t)N*32*4);   // bf16x2 packed u
    float*    v          = (float*)   alloc((size_t)N*64*4);
    float*    xA         = (float*)   alloc((size_t)N*64*4);
    float*    xB         = (float*)   alloc((size_t)N*64*4);
    unsigned* amax       = (unsigned*)alloc(3*4);
    float*    g          = (float*)   alloc(4096*4);
    int*      bsum       = (int*)     alloc(512*4);
    int*      bhist      = (int*)     alloc((size_t)NCHUNK*nbuk*4);
    int*      btot       = (int*)     alloc(256*4);
    int*      bbase0     = (int*)     alloc(256*4);
    int*      bbase      = (int*)     alloc((size_t)NCHUNK*nbuk*4);

    hipMemsetAsync(cnt,  0, (size_t)N*4, stream);
    hipMemsetAsync(amax, 0, 12, stream);
    hipMemsetAsync(g,    0, 4096*4, stream);

    // transform for layer 0 first: s1/s2 ready for fused edge-max in k_place
    k_xform<64,32><<<(NG*4+3)/4,256,0,stream>>>(x, fw[0], ww[0], ubf, v, s1, s2, N);

    k_hist_c <<<NCHUNK,256,0,stream>>>(tgt, cnt, bhist, E, shift, nbuk);
    k_scan1  <<<NB,  256,0,stream>>>(cnt, bsum, N);
    k_scan2  <<<1,   512,0,stream>>>(bsum, NB);
    k_scan3  <<<NB,  256,0,stream>>>(cnt, bsum, row_start, cursor, N);
    k_btot   <<<nbuk,256,0,stream>>>(bhist, btot, NCHUNK, nbuk);
    k_bbase0 <<<1,   256,0,stream>>>(btot, bbase0, nbuk);
    k_bbase  <<<nbuk,256,0,stream>>>(bhist, bbase0, bbase, NCHUNK, nbuk);
    k_place  <<<NCHUNK,256,0,stream>>>(src, tgt, bbase, ebuf, s1, s2, &amax[0], E, shift, nbuk);
    k_nscat  <<<2048,256,0,stream>>>(ebuf, cursor, sorted_src, E);

    // layer 0 aggregate
    k_prep<<<NB,256,0,stream>>>(s1, s2, &amax[0], N);
    k_aggregate2<32><<<2048,256,0,stream>>>(row_start, sorted_src, ubf, v, s1, s2, fb[0], xA, N);
    // layer 1: 32 -> 64
    k_xform<32,64><<<(NG*8+3)/4,256,0,stream>>>(xA, fw[1], ww[1], ubf, v, s1, s2, N);
    k_edge_max<<<1024,256,0,stream>>>(src, tgt, s1, s2, &amax[1], E);
    k_prep<<<NB,256,0,stream>>>(s1, s2, &amax[1], N);
    k_aggregate2<64><<<2048,256,0,stream>>>(row_start, sorted_src, ubf, v, s1, s2, fb[1], xB, N);
    // layer 2: 64 -> 64
    k_xform<64,64><<<(NG*8+3)/4,256,0,stream>>>(xB, fw[2], ww[2], ubf, v, s1, s2, N);
    k_edge_max<<<1024,256,0,stream>>>(src, tgt, s1, s2, &amax[2], E);
    k_prep<<<NB,256,0,stream>>>(s1, s2, &amax[2], N);
    k_aggregate2<64><<<2048,256,0,stream>>>(row_start, sorted_src, ubf, v, s1, s2, fb[2], xA, N);

    k_pool<<<128,1024,0,stream>>>(xA, gid, g, N);
    k_mlp <<<1,  1024,0,stream>>>(g, mw0, mb0, mw1, mb1, out);
}

// Round 8
// 497.822 us; speedup vs baseline: 2.0128x; 1.2184x over previous
//
#include <hip/hip_runtime.h>
#include <hip/hip_bf16.h>
#include <math.h>

#define NGRAPH 64
#define EPSV 1e-6f
#define CH 4096          // edges per partition chunk

__device__ __forceinline__ unsigned enc_f32(float f){
    unsigned u = __float_as_uint(f);
    return (u & 0x80000000u) ? ~u : (u | 0x80000000u);
}
__device__ __forceinline__ float dec_f32(unsigned u){
    return (u & 0x80000000u) ? __uint_as_float(u & 0x7FFFFFFFu) : __uint_as_float(~u);
}
__device__ __forceinline__ unsigned bf16_rn(float x){
    unsigned u = __float_as_uint(x);
    return (u + 0x7fffu + ((u>>16)&1u)) >> 16;
}
__device__ __forceinline__ float bflo(unsigned u){ return __uint_as_float(u<<16); }
__device__ __forceinline__ float bfhi(unsigned u){ return __uint_as_float(u & 0xffff0000u); }

// ---------------- bucket histogram: 2 sub-blocks per chunk, LDS-only + tiny global merge ----------------
__global__ __launch_bounds__(256) void k_hist_c(const int* __restrict__ tgt,
                                                int* __restrict__ bhist,
                                                int E, int shift, int nbuk){
    __shared__ int h[256];
    int t = threadIdx.x;
    h[t] = 0; __syncthreads();
    int blk = blockIdx.x;            // sub-block: 2048 edges
    int chunk = blk >> 1;
    int base = blk*2048;
    int lim  = base + 2048; if(lim > E) lim = E;
    for(int i=base+t; i<lim; i+=256)
        atomicAdd(&h[tgt[i]>>shift], 1);
    __syncthreads();
    if(t < nbuk && h[t]) atomicAdd(&bhist[chunk*nbuk + t], h[t]);
}

// per-bucket totals over chunks
__global__ __launch_bounds__(256) void k_btot(const int* __restrict__ bhist, int* __restrict__ btot,
                                              int nchunk, int nbuk){
    __shared__ int red[256];
    int b = blockIdx.x, t = threadIdx.x;
    int s = 0;
    for(int blk=t; blk<nchunk; blk+=256) s += bhist[blk*nbuk + b];
    red[t] = s; __syncthreads();
    for(int off=128; off>0; off>>=1){
        if(t<off) red[t] += red[t+off];
        __syncthreads();
    }
    if(t==0) btot[b] = red[0];
}

// exclusive scan of bucket totals
__global__ __launch_bounds__(256) void k_bbase0(const int* __restrict__ btot, int* __restrict__ bbase0, int nbuk){
    __shared__ int s[256];
    int t = threadIdx.x;
    int v = (t<nbuk) ? btot[t] : 0;
    s[t] = v; __syncthreads();
    for(int off=1; off<256; off<<=1){
        int a = (t>=off) ? s[t-off] : 0;
        __syncthreads();
        s[t] += a;
        __syncthreads();
    }
    if(t<nbuk) bbase0[t] = s[t] - v;
}

// per-(chunk,bucket) base (deterministic, atomic-free); nchunk <= 512
__global__ __launch_bounds__(512) void k_bbase(const int* __restrict__ bhist, const int* __restrict__ bbase0,
                                               int* __restrict__ bbase, int nchunk, int nbuk){
    __shared__ int s[512];
    int b = blockIdx.x, t = threadIdx.x;
    int v = (t<nchunk) ? bhist[t*nbuk + b] : 0;
    s[t] = v; __syncthreads();
    for(int off=1; off<512; off<<=1){
        int a = (t>=off) ? s[t-off] : 0;
        __syncthreads();
        s[t] += a;
        __syncthreads();
    }
    if(t<nchunk) bbase[t*nbuk + b] = bbase0[b] + s[t] - v;
}

// place edges into bucket-ordered ebuf via LDS tickets; fused exact layer-0 edge max (of e1*e2)
__global__ __launch_bounds__(256) void k_place(const int* __restrict__ src, const int* __restrict__ tgt,
                                               const int* __restrict__ bbase, int2* __restrict__ ebuf,
                                               const float* __restrict__ e1, const float* __restrict__ e2,
                                               unsigned* __restrict__ amax_enc,
                                               int E, int shift, int nbuk){
    __shared__ int lcur[256];
    __shared__ float wm[4];
    int t = threadIdx.x, blk = blockIdx.x;
    lcur[t] = (t<nbuk) ? bbase[blk*nbuk + t] : 0;
    __syncthreads();
    int base = blk*CH;
    int lim  = base + CH; if(lim > E) lim = E;
    float m = 0.f;
    for(int i=base+t; i<lim; i+=256){
        int ss = src[i], tt = tgt[i];
        m = fmaxf(m, e1[ss] * e2[tt]);
        int p = atomicAdd(&lcur[tt>>shift], 1);
        ebuf[p] = make_int2(ss, tt);
    }
    for(int off=32; off>0; off>>=1) m = fmaxf(m, __shfl_xor(m, off));
    if((t&63)==0) wm[t>>6] = m;
    __syncthreads();
    if(t==0){
        float mm = fmaxf(fmaxf(wm[0],wm[1]), fmaxf(wm[2],wm[3]));
        atomicMax(amax_enc, enc_f32(mm));
    }
}

// per-bucket local CSR: LDS histogram + scan -> row_start, LDS-ticket scatter -> sorted_src
__global__ __launch_bounds__(512) void k_sortb(const int2* __restrict__ ebuf,
                                               const int* __restrict__ bbase0, const int* __restrict__ btot,
                                               int* __restrict__ row_start, int* __restrict__ sorted_src,
                                               int N, int E, int shift, int nbuk){
    __shared__ int sc[512];
    int b = blockIdx.x, t = threadIdx.x;
    int ebeg = bbase0[b];
    int eend = ebeg + btot[b];
    int nbeg = b << shift;
    int nloc = N - nbeg; if(nloc > 512) nloc = 512;
    sc[t] = 0; __syncthreads();
    for(int i=ebeg+t; i<eend; i+=512)
        atomicAdd(&sc[ebuf[i].y - nbeg], 1);
    __syncthreads();
    int v = sc[t];
    for(int off=1; off<512; off<<=1){
        int a = (t>=off) ? sc[t-off] : 0;
        __syncthreads();
        sc[t] += a;
        __syncthreads();
    }
    int pos0 = ebeg + sc[t] - v;      // global exclusive prefix
    if(t < nloc) row_start[nbeg + t] = pos0;
    if(b == nbuk-1 && t == 0) row_start[N] = E;
    __syncthreads();
    sc[t] = pos0;                     // becomes cursor
    __syncthreads();
    for(int i=ebeg+t; i<eend; i+=512){
        int2 e = ebuf[i];
        int p = atomicAdd(&sc[e.y - nbeg], 1);
        sorted_src[p] = e.x;
    }
}

// ---------------- exact global edge max of e1*e2 (layers 1,2), x4 unrolled ----------------
__global__ __launch_bounds__(256) void k_edge_max(const int* __restrict__ src, const int* __restrict__ tgt,
                           const float* __restrict__ e1, const float* __restrict__ e2,
                           unsigned* __restrict__ amax_enc, int E){
    int i4 = (blockIdx.x*256 + threadIdx.x)*4;
    int stride = gridDim.x*256*4;
    float m = 0.f;
    for(; i4+3 < E; i4 += stride){
        int4 s4 = *reinterpret_cast<const int4*>(&src[i4]);
        int4 t4 = *reinterpret_cast<const int4*>(&tgt[i4]);
        float a0 = e1[s4.x]*e2[t4.x], a1 = e1[s4.y]*e2[t4.y];
        float a2 = e1[s4.z]*e2[t4.z], a3 = e1[s4.w]*e2[t4.w];
        m = fmaxf(m, fmaxf(fmaxf(a0,a1), fmaxf(a2,a3)));
    }
    for(; i4 < E; i4++) m = fmaxf(m, e1[src[i4]] * e2[tgt[i4]]);
    for(int off=32; off>0; off>>=1) m = fmaxf(m, __shfl_xor(m, off));
    if((threadIdx.x & 63)==0) atomicMax(amax_enc, enc_f32(m));
}

// ---------------- node transform: wave = 64 nodes x one 16-col slice ----------------
// u packed bf16; e1=exp(s1), e2=exp(s2) written directly (no prep pass).
template<int DI, int DO>
__global__ __launch_bounds__(256) void k_xform(
    const float* __restrict__ x, const float* __restrict__ fw,
    const float* __restrict__ ww,
    unsigned* __restrict__ ubf, float* __restrict__ v,
    float* __restrict__ e1, float* __restrict__ e2, int N)
{
    constexpr int NSLICE = 2*DO/16;
    constexpr int CP = DO/2;
    int lane = threadIdx.x & 63;
    int wid  = __builtin_amdgcn_readfirstlane(threadIdx.x >> 6);
    int wg   = blockIdx.x*4 + wid;
    int ngroups = (N+63)>>6;
    if(wg >= ngroups*NSLICE) return;
    int slice = wg % NSLICE;
    int group = wg / NSLICE;
    int n  = group*64 + lane;
    bool act = n < N;
    int nn = act ? n : N-1;
    bool uhalf = slice < DO/16;
    int scol = (slice & (DO/16 - 1))*16;
    const float* wp  = fw + (uhalf ? 0 : DI*DO) + scol;
    const float* wwp = ww + (uhalf ? 0 : DI);
    float acc[16];
    #pragma unroll
    for(int j=0;j<16;j++) acc[j]=0.f;
    float p = 0.f;
    #pragma unroll
    for(int k4=0;k4<DI/4;k4++){
        float4 xv = *reinterpret_cast<const float4*>(&x[(size_t)nn*DI + k4*4]);
        #pragma unroll
        for(int kk=0;kk<4;kk++){
            float xk = (kk==0)?xv.x:(kk==1)?xv.y:(kk==2)?xv.z:xv.w;
            int k = k4*4+kk;
            p = fmaf(xk, wwp[k], p);
            #pragma unroll
            for(int j=0;j<16;j++) acc[j] = fmaf(xk, wp[k*DO + j], acc[j]);
        }
    }
    if(act){
        if(uhalf){
            unsigned pk[8];
            #pragma unroll
            for(int j=0;j<8;j++)
                pk[j] = bf16_rn(acc[2*j]) | (bf16_rn(acc[2*j+1])<<16);
            unsigned* dst = &ubf[(size_t)n*CP + scol/2];
            *reinterpret_cast<uint4*>(dst)   = make_uint4(pk[0],pk[1],pk[2],pk[3]);
            *reinterpret_cast<uint4*>(dst+4) = make_uint4(pk[4],pk[5],pk[6],pk[7]);
        } else {
            #pragma unroll
            for(int j4=0;j4<4;j4++)
                *reinterpret_cast<float4*>(&v[(size_t)n*DO + scol + j4*4]) =
                    make_float4(acc[j4*4],acc[j4*4+1],acc[j4*4+2],acc[j4*4+3]);
        }
        if(scol==0) (uhalf ? e1 : e2)[n] = __expf(p);
    }
}

// ---------------- edge softmax + aggregate: lane = channel PAIR ----------------
// out = num/(den + eps*eA) with p = e1[src]*e2[tgt]; eA = max edge product.
template<int DO>
__global__ __launch_bounds__(256) void k_aggregate2(
    const int* __restrict__ row_start, const int* __restrict__ sorted_src,
    const unsigned* __restrict__ ubf, const float* __restrict__ v,
    const float* __restrict__ e1, const float* __restrict__ e2,
    const float* __restrict__ fb,
    const unsigned* __restrict__ amax_enc,
    float* __restrict__ xout, int N)
{
    constexpr int CP = DO/2;
    constexpr int PN = 64/CP;
    float epsA = EPSV * dec_f32(*amax_enc);
    int lane = threadIdx.x & 63;
    int wid  = threadIdx.x >> 6;
    int c2   = lane & (CP-1);
    int grp  = lane >> (CP==32 ? 5 : 4);
    float fx = fb[2*c2], fy = fb[2*c2+1];
    int gw = blockIdx.x*4 + wid;
    int nwaves = gridDim.x*4;
    for(int n=gw; n<N; n+=nwaves){
        float2 vv = *reinterpret_cast<const float2*>(&v[(size_t)n*DO + 2*c2]);
        float wx = vv.x + fx, wy = vv.y + fy;
        float e2n = e2[n];
        int beg = row_start[n], end = row_start[n+1];
        float ax = 0.f, ay = 0.f, den = 0.f;
        int idx = beg + grp;
        for(; idx + 3*PN < end; idx += 4*PN){
            int sA = sorted_src[idx];
            int sB = sorted_src[idx+PN];
            int sC = sorted_src[idx+2*PN];
            int sD = sorted_src[idx+3*PN];
            float eA = e1[sA], eB = e1[sB], eC = e1[sC], eD = e1[sD];
            unsigned uA = ubf[(size_t)sA*CP+c2], uB = ubf[(size_t)sB*CP+c2];
            unsigned uC = ubf[(size_t)sC*CP+c2], uD = ubf[(size_t)sD*CP+c2];
            float pA = eA*e2n, pB = eB*e2n, pC = eC*e2n, pD = eD*e2n;
            den += (pA+pB)+(pC+pD);
            ax = fmaf(pA, fmaxf(bflo(uA)+wx,0.f), ax);
            ay = fmaf(pA, fmaxf(bfhi(uA)+wy,0.f), ay);
            ax = fmaf(pB, fmaxf(bflo(uB)+wx,0.f), ax);
            ay = fmaf(pB, fmaxf(bfhi(uB)+wy,0.f), ay);
            ax = fmaf(pC, fmaxf(bflo(uC)+wx,0.f), ax);
            ay = fmaf(pC, fmaxf(bfhi(uC)+wy,0.f), ay);
            ax = fmaf(pD, fmaxf(bflo(uD)+wx,0.f), ax);
            ay = fmaf(pD, fmaxf(bfhi(uD)+wy,0.f), ay);
        }
        for(; idx < end; idx += PN){
            int s = sorted_src[idx];
            float e = e1[s];
            unsigned uu = ubf[(size_t)s*CP+c2];
            float p = e*e2n;
            den += p;
            ax = fmaf(p, fmaxf(bflo(uu)+wx,0.f), ax);
            ay = fmaf(p, fmaxf(bfhi(uu)+wy,0.f), ay);
        }
        #pragma unroll
        for(int off=CP; off<64; off<<=1){
            den += __shfl_xor(den, off);
            ax  += __shfl_xor(ax , off);
            ay  += __shfl_xor(ay , off);
        }
        if(lane < CP){
            float d = den + epsA;
            *reinterpret_cast<float2*>(&xout[(size_t)n*DO + 2*c2]) =
                make_float2(ax/d, ay/d);
        }
    }
}

// ---------------- graph pooling ----------------
__global__ __launch_bounds__(1024) void k_pool(const float* __restrict__ x, const int* __restrict__ gid,
                        float* __restrict__ g, int N){
    __shared__ float bins[64*64];
    int t = threadIdx.x;
    for(int i=t;i<4096;i+=1024) bins[i]=0.f;
    __syncthreads();
    int lane = t & 63, wid = t>>6;
    int gw = blockIdx.x*16 + wid;
    int nwaves = gridDim.x*16;
    for(int n=gw; n<N; n+=nwaves){
        int gi = gid[n];
        atomicAdd(&bins[gi*64 + lane], x[(size_t)n*64 + lane]);
    }
    __syncthreads();
    for(int i=t;i<4096;i+=1024){
        float b = bins[i];
        if(b != 0.f) atomicAdd(&g[i], b);
    }
}

// ---------------- tiny MLP head ----------------
__global__ __launch_bounds__(1024) void k_mlp(const float* __restrict__ g,
        const float* __restrict__ mw0, const float* __restrict__ mb0,
        const float* __restrict__ mw1, const float* __restrict__ mb1,
        float* __restrict__ out){
    __shared__ float lg[64*64];
    __shared__ float hid[64*32];
    int t = threadIdx.x;
    for(int i=t;i<4096;i+=1024) lg[i]=g[i];
    __syncthreads();
    for(int i=t;i<2048;i+=1024){
        int r = i>>5, h = i&31;
        float a = mb0[h];
        for(int k=0;k<64;k++) a = fmaf(lg[r*64+k], mw0[k*32+h], a);
        hid[i] = fmaxf(a, 0.f);
    }
    __syncthreads();
    for(int i=t;i<640;i+=1024){
        int r = i/10, j = i%10;
        float a = mb1[j];
        for(int h=0;h<32;h++) a = fmaf(hid[r*32+h], mw1[h*10+j], a);
        out[i] = a;
    }
}

extern "C" void kernel_launch(void* const* d_in, const int* in_sizes, int n_in,
                              void* d_out, int out_size, void* d_ws, size_t ws_size,
                              hipStream_t stream){
    const float* x   = (const float*)d_in[0];
    const int*   src = (const int*)d_in[1];
    const int*   tgt = (const int*)d_in[2];
    const int*   gid = (const int*)d_in[3];
    const float* fw[3] = {(const float*)d_in[4],  (const float*)d_in[8],  (const float*)d_in[12]};
    const float* fb[3] = {(const float*)d_in[5],  (const float*)d_in[9],  (const float*)d_in[13]};
    const float* ww[3] = {(const float*)d_in[6],  (const float*)d_in[10], (const float*)d_in[14]};
    const float* mw0 = (const float*)d_in[16];
    const float* mb0 = (const float*)d_in[17];
    const float* mw1 = (const float*)d_in[18];
    const float* mb1 = (const float*)d_in[19];
    float* out = (float*)d_out;

    const int N = in_sizes[3];
    const int E = in_sizes[1];
    const int NG = (N + 63)/64;
    const int NCHUNK = (E + CH - 1)/CH;          // 391 for E=1.6M
    int shift = 0;
    while(((N-1)>>shift) >= 256) shift++;        // 512 nodes/bucket, nbuk<=256
    const int nbuk = ((N-1)>>shift) + 1;

    char* ws = (char*)d_ws;
    size_t off = 0;
    auto alloc = [&](size_t bytes)->char*{
        char* p = ws + off;
        off += (bytes + 255) & ~(size_t)255;
        return p;
    };
    int*      row_start  = (int*)     alloc((size_t)(N+1)*4);
    int*      sorted_src = (int*)     alloc((size_t)E*4);
    int2*     ebuf       = (int2*)    alloc((size_t)E*8);
    float*    e1         = (float*)   alloc((size_t)N*4);
    float*    e2         = (float*)   alloc((size_t)N*4);
    unsigned* ubf        = (unsigned*)alloc((size_t)N*32*4);
    float*    v          = (float*)   alloc((size_t)N*64*4);
    float*    xA         = (float*)   alloc((size_t)N*64*4);
    float*    xB         = (float*)   alloc((size_t)N*64*4);
    unsigned* amax       = (unsigned*)alloc(3*4);
    float*    g          = (float*)   alloc(4096*4);
    int*      bhist      = (int*)     alloc((size_t)NCHUNK*nbuk*4);
    int*      btot       = (int*)     alloc(256*4);
    int*      bbase0     = (int*)     alloc(256*4);
    int*      bbase      = (int*)     alloc((size_t)NCHUNK*nbuk*4);

    hipMemsetAsync(amax,  0, 12, stream);
    hipMemsetAsync(g,     0, 4096*4, stream);
    hipMemsetAsync(bhist, 0, (size_t)NCHUNK*nbuk*4, stream);

    // layer-0 transform first: e1/e2 ready for fused edge-max inside k_place
    k_xform<64,32><<<(NG*4+3)/4,256,0,stream>>>(x, fw[0], ww[0], ubf, v, e1, e2, N);

    k_hist_c <<<NCHUNK*2,256,0,stream>>>(tgt, bhist, E, shift, nbuk);
    k_btot   <<<nbuk,256,0,stream>>>(bhist, btot, NCHUNK, nbuk);
    k_bbase0 <<<1,   256,0,stream>>>(btot, bbase0, nbuk);
    k_bbase  <<<nbuk,512,0,stream>>>(bhist, bbase0, bbase, NCHUNK, nbuk);
    k_place  <<<NCHUNK,256,0,stream>>>(src, tgt, bbase, ebuf, e1, e2, &amax[0], E, shift, nbuk);
    k_sortb  <<<nbuk,512,0,stream>>>(ebuf, bbase0, btot, row_start, sorted_src, N, E, shift, nbuk);

    // layer 0 aggregate
    k_aggregate2<32><<<2048,256,0,stream>>>(row_start, sorted_src, ubf, v, e1, e2, fb[0], &amax[0], xA, N);
    // layer 1: 32 -> 64
    k_xform<32,64><<<(NG*8+3)/4,256,0,stream>>>(xA, fw[1], ww[1], ubf, v, e1, e2, N);
    k_edge_max<<<1024,256,0,stream>>>(src, tgt, e1, e2, &amax[1], E);
    k_aggregate2<64><<<2048,256,0,stream>>>(row_start, sorted_src, ubf, v, e1, e2, fb[1], &amax[1], xB, N);
    // layer 2: 64 -> 64
    k_xform<64,64><<<(NG*8+3)/4,256,0,stream>>>(xB, fw[2], ww[2], ubf, v, e1, e2, N);
    k_edge_max<<<1024,256,0,stream>>>(src, tgt, e1, e2, &amax[2], E);
    k_aggregate2<64><<<2048,256,0,stream>>>(row_start, sorted_src, ubf, v, e1, e2, fb[2], &amax[2], xA, N);

    k_pool<<<128,1024,0,stream>>>(xA, gid, g, N);
    k_mlp <<<1,  1024,0,stream>>>(g, mw0, mb0, mw1, mb1, out);
}